// Round 1
// 1324.985 us; speedup vs baseline: 1.1226x; 1.1226x over previous
//
#include <hip/hip_runtime.h>
#include <cstdint>
#include <cstddef>

#define A_N 100000
#define B_N 200000
#define M_N 20000
#define POOL_N 220000   // M_N + B_N
#define HD 256
#define MAX_NB 10
#define N_MOLS 2000
#define ATOM_FDIM 35
#define FB_DIM 40

typedef unsigned short u16;
typedef __attribute__((ext_vector_type(8))) short bf16x8;
typedef __attribute__((ext_vector_type(4))) float f32x4;

// Static device buffers (BSS, ~646 MB).
__device__ u16 g_msg0[(size_t)B_N * HD];      // bf16 messages (ping)
__device__ u16 g_msg1[(size_t)B_N * HD];      // bf16 messages (pong)
__device__ u16 g_tmsgh[(size_t)M_N * HD];     // bf16 tree messages
__device__ u16 g_P[(size_t)POOL_N * HD];      // P = pool @ W_h   (bf16)
__device__ u16 g_Q[(size_t)POOL_N * HD];      // Q = pool @ Wo[35:291] (bf16)
__device__ u16 g_binH[(size_t)B_N * HD];      // bf16 binput
__device__ float g_F[(size_t)A_N * HD];       // fp32 fatoms@Wo_top + bias
// packed split-bf16 weights in MFMA A-fragment order: [(c*16+t)*64+lane]*8+j
__device__ u16 g_pWh_hi[65536], g_pWh_lo[65536];
__device__ u16 g_pWo_hi[65536], g_pWo_lo[65536];
__device__ float g_counts[N_MOLS];

__device__ __forceinline__ u16 f2b(float f)
{
    union { float f; unsigned u; } x; x.f = f;
    const unsigned r = x.u + 0x7FFFu + ((x.u >> 16) & 1u);
    return (u16)(r >> 16);
}
__device__ __forceinline__ float b2f(u16 h) { return __uint_as_float((unsigned)h << 16); }
__device__ __forceinline__ float blo(unsigned u) { return __uint_as_float(u << 16); }
__device__ __forceinline__ float bhi(unsigned u) { return __uint_as_float(u & 0xffff0000u); }

// ---------------- setup kernels ----------------
__global__ __launch_bounds__(256)
void k_zero_out(float* __restrict__ p, int n)
{
    const int i = blockIdx.x * 256 + threadIdx.x;
    if (i < n) p[i] = 0.f;
}

__global__ __launch_bounds__(256)
void k_zero_counts()
{
    const int i = blockIdx.x * 256 + threadIdx.x;
    if (i < N_MOLS) g_counts[i] = 0.f;
}

__global__ __launch_bounds__(256)
void k_cvt(const float* __restrict__ tmsg)
{
    const int i = (blockIdx.x * 256 + threadIdx.x) * 4;
    if (i < M_N * HD) {
        const float4 v = *(const float4*)(tmsg + i);
        ushort4 o;
        o.x = f2b(v.x); o.y = f2b(v.y); o.z = f2b(v.z); o.w = f2b(v.w);
        *(ushort4*)(g_tmsgh + i) = o;
    }
}

// pack Wh and Wo[35:291] into split-bf16 MFMA A-fragment layout.
//   packed[((c*16+t)*64+lane)*8+j] = W[c*32+(lane>>4)*8+j][t*16+(lane&15)]
__global__ __launch_bounds__(256)
void k_packW(const float* __restrict__ Wh, const float* __restrict__ Wo)
{
    const int id = blockIdx.x * 256 + threadIdx.x;   // 0..8191
    if (id >= 8192) return;
    const int l = id & 63;
    const int t = (id >> 6) & 15;
    const int c = id >> 10;
    const int n = t * 16 + (l & 15);
    const int kb = c * 32 + ((l >> 4) << 3);
    const size_t base = (size_t)id * 8;
    #pragma unroll
    for (int j = 0; j < 8; ++j) {
        const int k = kb + j;
        const float wh = Wh[(size_t)k * HD + n];
        const u16 hh = f2b(wh);
        g_pWh_hi[base + j] = hh;
        g_pWh_lo[base + j] = f2b(wh - b2f(hh));
        const float wo = Wo[(size_t)(35 + k) * HD + n];
        const u16 oh = f2b(wo);
        g_pWo_hi[base + j] = oh;
        g_pWo_lo[base + j] = f2b(wo - b2f(oh));
    }
}

// ---------------- K1: binH = bf16(fbonds @ W_i); msg0 = bf16(relu(binput)) ----------------
__global__ __launch_bounds__(256)
void k_in(const float* __restrict__ fbonds, const float* __restrict__ Wi)
{
    __shared__ float Ws[FB_DIM * HD];                      // 40 KB
    for (int i = threadIdx.x; i < FB_DIM * HD; i += 256) Ws[i] = Wi[i];
    __syncthreads();
    const int lane = threadIdx.x & 63;
    const int wid  = (blockIdx.x * 256 + threadIdx.x) >> 6;
    const int nw   = (gridDim.x * 256) >> 6;
    for (int row = wid; row < B_N; row += nw) {
        const float* fr = fbonds + (size_t)row * FB_DIM;
        float ax = 0.f, ay = 0.f, az = 0.f, aw = 0.f;
        #pragma unroll
        for (int q = 0; q < FB_DIM / 4; ++q) {
            const float4 fv = *(const float4*)(fr + q * 4);
            const float fa[4] = {fv.x, fv.y, fv.z, fv.w};
            #pragma unroll
            for (int t = 0; t < 4; ++t) {
                const float4 w = *(const float4*)&Ws[(q * 4 + t) * HD + lane * 4];
                ax += fa[t] * w.x; ay += fa[t] * w.y;
                az += fa[t] * w.z; aw += fa[t] * w.w;
            }
        }
        const size_t base = (size_t)row * HD + lane * 4;
        ushort4 bi;
        bi.x = f2b(ax); bi.y = f2b(ay); bi.z = f2b(az); bi.w = f2b(aw);
        *(ushort4*)(g_binH + base) = bi;
        ushort4 o;
        o.x = f2b(fmaxf(ax, 0.f)); o.y = f2b(fmaxf(ay, 0.f));
        o.z = f2b(fmaxf(az, 0.f)); o.w = f2b(fmaxf(aw, 0.f));
        *(ushort4*)(g_msg0 + base) = o;
    }
}

// ------- K2: MFMA GEMM — dst[row] = bf16(pool[row] @ W) with split-bf16 W -------
// R11: previous wave tile was 16 rows x 128 cols -> every wave streamed its full
// 131 KB weight slice from L2 per 16 rows = 1.8 GB L2 traffic per GEMM
// (~52 us/CU floor, 2x the MFMA floor). New wave tile = 64 rows x 128 cols
// (block = 128 rows x 256 cols): each ah/al fragment feeds 4 MFMAs, weight
// traffic drops 4x to 450 MB. acc[4][8] f32x4 = 128 VGPR; all rg/t indexing is
// compile-time static (only the c-loop is a runtime loop; acc never indexed by
// c) so nothing spills to scratch (the R10 trap).
__global__ __launch_bounds__(256, 2)
void k_gemmMF(int sel, int rowStart, int rowEnd)
{
    const u16* msrc = (sel == 1) ? g_msg1 : g_msg0;
    const u16* pHi  = (sel == 2) ? g_pWo_hi : g_pWh_hi;
    const u16* pLo  = (sel == 2) ? g_pWo_lo : g_pWh_lo;
    u16* dst        = (sel == 2) ? g_Q : g_P;

    const int tid  = threadIdx.x;
    const int lane = tid & 63;
    const int wv   = tid >> 6;            // 0..3
    const int l15  = lane & 15;
    const int quad = lane >> 4;
    const int tOff = (wv & 1) * 8;        // col-half: tiles [tOff, tOff+8)

    // 4 row-groups of 16 rows each: wave covers 64 rows x 128 cols.
    int rowIdeal[4];
    const u16* srow[4];
    #pragma unroll
    for (int rg = 0; rg < 4; ++rg) {
        const int ri = rowStart + blockIdx.x * 128 + (wv >> 1) * 64 + rg * 16 + l15;
        rowIdeal[rg] = ri;
        const int r = (ri < rowEnd) ? ri : (rowEnd - 1);
        srow[rg] = (r < M_N) ? (g_tmsgh + (size_t)r * HD)
                             : (msrc + (size_t)(r - M_N) * HD);
    }

    f32x4 acc[4][8];
    #pragma unroll
    for (int rg = 0; rg < 4; ++rg)
        #pragma unroll
        for (int t = 0; t < 8; ++t)
            acc[rg][t] = (f32x4){0.f, 0.f, 0.f, 0.f};

    #pragma unroll 1
    for (int c = 0; c < 8; ++c) {
        bf16x8 b[4];
        #pragma unroll
        for (int rg = 0; rg < 4; ++rg)
            b[rg] = *(const bf16x8*)(srow[rg] + c * 32 + quad * 8);
        const u16* ph = pHi + ((size_t)(c * 16 + tOff) * 64 + lane) * 8;
        const u16* pl = pLo + ((size_t)(c * 16 + tOff) * 64 + lane) * 8;
        #pragma unroll
        for (int t = 0; t < 8; ++t) {
            const bf16x8 ah = *(const bf16x8*)(ph + (size_t)t * 512);
            #pragma unroll
            for (int rg = 0; rg < 4; ++rg)
                acc[rg][t] = __builtin_amdgcn_mfma_f32_16x16x32_bf16(ah, b[rg], acc[rg][t], 0, 0, 0);
            const bf16x8 al = *(const bf16x8*)(pl + (size_t)t * 512);
            #pragma unroll
            for (int rg = 0; rg < 4; ++rg)
                acc[rg][t] = __builtin_amdgcn_mfma_f32_16x16x32_bf16(al, b[rg], acc[rg][t], 0, 0, 0);
        }
    }

    #pragma unroll
    for (int rg = 0; rg < 4; ++rg) {
        if (rowIdeal[rg] < rowEnd) {
            u16* drow = dst + (size_t)rowIdeal[rg] * HD + tOff * 16 + quad * 4;
            #pragma unroll
            for (int t = 0; t < 8; ++t) {
                ushort4 o;
                o.x = f2b(acc[rg][t][0]); o.y = f2b(acc[rg][t][1]);
                o.z = f2b(acc[rg][t][2]); o.w = f2b(acc[rg][t][3]);
                *(ushort4*)(drow + t * 16) = o;
            }
        }
    }
}

// ------- K3: dst = bf16(relu(binH + sum_j P[bgraph[r][j]])) — pure gather -------
__global__ __launch_bounds__(256)
void k_gather(const int* __restrict__ bgraph, int dstSel)
{
    u16* dst = dstSel ? g_msg1 : g_msg0;
    __shared__ int idx_s[8][MAX_NB];
    const int tid = threadIdx.x;
    const int rowBase = blockIdx.x * 8;
    if (tid < 8 * MAX_NB) {
        const int r = tid / MAX_NB;
        const int j = tid - r * MAX_NB;
        idx_s[r][j] = bgraph[(size_t)(rowBase + r) * MAX_NB + j];
    }
    __syncthreads();
    const int rl = tid >> 5;           // [0,8)
    const int c  = (tid & 31) << 3;    // 8 bf16 = 16 B per thread
    const int row = rowBase + rl;

    float s[8] = {0.f,0.f,0.f,0.f,0.f,0.f,0.f,0.f};
    #pragma unroll
    for (int j = 0; j < MAX_NB; ++j) {
        const uint4 v = *(const uint4*)(g_P + (size_t)idx_s[rl][j] * HD + c);
        s[0] += blo(v.x); s[1] += bhi(v.x);
        s[2] += blo(v.y); s[3] += bhi(v.y);
        s[4] += blo(v.z); s[5] += bhi(v.z);
        s[6] += blo(v.w); s[7] += bhi(v.w);
    }
    const uint4 bv = *(const uint4*)(g_binH + (size_t)row * HD + c);
    uint4 w;
    w.x = ((unsigned)f2b(fmaxf(s[0] + blo(bv.x), 0.f)))
        | ((unsigned)f2b(fmaxf(s[1] + bhi(bv.x), 0.f)) << 16);
    w.y = ((unsigned)f2b(fmaxf(s[2] + blo(bv.y), 0.f)))
        | ((unsigned)f2b(fmaxf(s[3] + bhi(bv.y), 0.f)) << 16);
    w.z = ((unsigned)f2b(fmaxf(s[4] + blo(bv.z), 0.f)))
        | ((unsigned)f2b(fmaxf(s[5] + bhi(bv.z), 0.f)) << 16);
    w.w = ((unsigned)f2b(fmaxf(s[6] + blo(bv.w), 0.f)))
        | ((unsigned)f2b(fmaxf(s[7] + bhi(bv.w), 0.f)) << 16);
    *(uint4*)(dst + (size_t)row * HD + c) = w;
}

// ------- K4: F = fatoms @ Wo[0:35] + bias (fp32) -------
__global__ __launch_bounds__(256)
void k_F(const float* __restrict__ fatoms, const float* __restrict__ Wo,
         const float* __restrict__ bias)
{
    __shared__ float Ws[ATOM_FDIM * HD];   // 35 KB
    __shared__ float bs[HD];
    for (int i = threadIdx.x; i < ATOM_FDIM * HD; i += 256) Ws[i] = Wo[i];
    for (int i = threadIdx.x; i < HD; i += 256) bs[i] = bias[i];
    __syncthreads();
    const int lane = threadIdx.x & 63;
    const int wid  = (blockIdx.x * 256 + threadIdx.x) >> 6;
    const int nw   = (gridDim.x * 256) >> 6;
    for (int row = wid; row < A_N; row += nw) {
        const float* fr = fatoms + (size_t)row * ATOM_FDIM;
        const float4 b4 = *(const float4*)&bs[lane * 4];
        float ax = b4.x, ay = b4.y, az = b4.z, aw = b4.w;
        #pragma unroll 5
        for (int k = 0; k < ATOM_FDIM; ++k) {
            const float f = fr[k];
            const float4 w = *(const float4*)&Ws[k * HD + lane * 4];
            ax += f * w.x; ay += f * w.y; az += f * w.z; aw += f * w.w;
        }
        float4 o; o.x = ax; o.y = ay; o.z = az; o.w = aw;
        *(float4*)(g_F + (size_t)row * HD + lane * 4) = o;
    }
}

// ------- K5: out[mol] += relu(F[a] + sum_j Q[agraph[a][j]]) — gather + segsum -------
__global__ __launch_bounds__(256)
void k_gatherA(const int* __restrict__ agraph, const int* __restrict__ scope,
               float* __restrict__ out)
{
    __shared__ int idx_s[64 * MAX_NB];
    __shared__ int sc_s[64];
    const int tid = threadIdx.x;
    const int rb = blockIdx.x * 64;
    for (int i = tid; i < 64 * MAX_NB; i += 256) {
        const int a = rb + i / MAX_NB;
        idx_s[i] = (a < A_N) ? agraph[(size_t)a * MAX_NB + (i % MAX_NB)] : 0;
    }
    if (tid < 64) sc_s[tid] = (rb + tid < A_N) ? scope[rb + tid] : -1;
    __syncthreads();

    const int grp = tid >> 5;          // 8 atoms per group, processed sequentially
    const int c = (tid & 31) * 8;      // 8 cols per thread
    float s[8] = {0.f,0.f,0.f,0.f,0.f,0.f,0.f,0.f};
    int prev = -1;
    #pragma unroll 1
    for (int i = 0; i < 8; ++i) {
        const int al = grp * 8 + i;
        const int a = rb + al;
        if (a < A_N) {
            const int m = sc_s[al];
            if (m != prev) {
                if (prev >= 0) {
                    float* dst = out + (size_t)prev * HD + c;
                    #pragma unroll
                    for (int q = 0; q < 8; ++q) atomicAdd(dst + q, s[q]);
                    #pragma unroll
                    for (int q = 0; q < 8; ++q) s[q] = 0.f;
                }
                prev = m;
            }
            float g0=0.f,g1=0.f,g2=0.f,g3=0.f,g4=0.f,g5=0.f,g6=0.f,g7=0.f;
            #pragma unroll
            for (int j = 0; j < MAX_NB; ++j) {
                const uint4 v = *(const uint4*)(g_Q + (size_t)idx_s[al * MAX_NB + j] * HD + c);
                g0 += blo(v.x); g1 += bhi(v.x);
                g2 += blo(v.y); g3 += bhi(v.y);
                g4 += blo(v.z); g5 += bhi(v.z);
                g6 += blo(v.w); g7 += bhi(v.w);
            }
            const float4 f0 = *(const float4*)(g_F + (size_t)a * HD + c);
            const float4 f1 = *(const float4*)(g_F + (size_t)a * HD + c + 4);
            s[0] += fmaxf(g0 + f0.x, 0.f); s[1] += fmaxf(g1 + f0.y, 0.f);
            s[2] += fmaxf(g2 + f0.z, 0.f); s[3] += fmaxf(g3 + f0.w, 0.f);
            s[4] += fmaxf(g4 + f1.x, 0.f); s[5] += fmaxf(g5 + f1.y, 0.f);
            s[6] += fmaxf(g6 + f1.z, 0.f); s[7] += fmaxf(g7 + f1.w, 0.f);
        }
    }
    if (prev >= 0) {
        float* dst = out + (size_t)prev * HD + c;
        #pragma unroll
        for (int q = 0; q < 8; ++q) atomicAdd(dst + q, s[q]);
    }
}

// ---------------- counts + divide ----------------
__global__ __launch_bounds__(256)
void k_counts(const int* __restrict__ scope)
{
    const int a = blockIdx.x * 256 + threadIdx.x;
    if (a < A_N) atomicAdd(&g_counts[scope[a]], 1.0f);
}

__global__ __launch_bounds__(256)
void k_div(float* __restrict__ out)
{
    const int idx = blockIdx.x * 256 + threadIdx.x;
    out[idx] = out[idx] / fmaxf(g_counts[idx >> 8], 1.0f);
}

// ---------------- launch ----------------
extern "C" void kernel_launch(void* const* d_in, const int* in_sizes, int n_in,
                              void* d_out, int out_size, void* d_ws, size_t ws_size,
                              hipStream_t stream)
{
    const float* fatoms = (const float*)d_in[0];
    const float* fbonds = (const float*)d_in[1];
    const int*   agraph = (const int*)d_in[2];
    const int*   bgraph = (const int*)d_in[3];
    const float* tmsg   = (const float*)d_in[4];
    const int*   scope  = (const int*)d_in[5];
    const float* W_i    = (const float*)d_in[6];
    const float* W_h    = (const float*)d_in[7];
    const float* W_o    = (const float*)d_in[8];
    const float* W_ob   = (const float*)d_in[9];
    float* out = (float*)d_out;

    (void)d_ws; (void)ws_size;

    k_zero_out<<<(N_MOLS * HD + 255) / 256, 256, 0, stream>>>(out, N_MOLS * HD);
    k_zero_counts<<<(N_MOLS + 255) / 256, 256, 0, stream>>>();
    k_cvt<<<(M_N * HD / 4 + 255) / 256, 256, 0, stream>>>(tmsg);
    k_packW<<<32, 256, 0, stream>>>(W_h, W_o);

    k_in<<<4096, 256, 0, stream>>>(fbonds, W_i);            // binH + msg0

    // iter 0: P = [tmsg; msg0] @ Wh; msg1 = relu(binH + gatherP)
    k_gemmMF<<<(POOL_N + 127) / 128, 256, 0, stream>>>(0, 0, POOL_N);
    k_gather<<<B_N / 8, 256, 0, stream>>>(bgraph, 1);
    // iter 1: only msg rows of P change
    k_gemmMF<<<(B_N + 127) / 128, 256, 0, stream>>>(1, M_N, POOL_N);
    k_gather<<<B_N / 8, 256, 0, stream>>>(bgraph, 0);

    // readout: Q = [tmsg; msg0] @ Wo[35:291]; F = fatoms@Wo[0:35]+b; gather+segsum
    k_gemmMF<<<(POOL_N + 127) / 128, 256, 0, stream>>>(2, 0, POOL_N);
    k_F<<<2048, 256, 0, stream>>>(fatoms, W_o, W_ob);
    k_counts<<<(A_N + 255) / 256, 256, 0, stream>>>(scope);
    k_gatherA<<<(A_N + 63) / 64, 256, 0, stream>>>(agraph, scope, out);
    k_div<<<(N_MOLS * HD) / 256, 256, 0, stream>>>(out);
}

// Round 2
// 1309.808 us; speedup vs baseline: 1.1356x; 1.0116x over previous
//
#include <hip/hip_runtime.h>
#include <cstdint>
#include <cstddef>

#define A_N 100000
#define B_N 200000
#define M_N 20000
#define POOL_N 220000   // M_N + B_N
#define HD 256
#define MAX_NB 10
#define N_MOLS 2000
#define ATOM_FDIM 35
#define FB_DIM 40

typedef unsigned short u16;
typedef __attribute__((ext_vector_type(8))) short bf16x8;
typedef __attribute__((ext_vector_type(4))) float f32x4;

// Static device buffers (BSS, ~646 MB).
__device__ u16 g_msg0[(size_t)B_N * HD];      // bf16 messages (ping)
__device__ u16 g_msg1[(size_t)B_N * HD];      // bf16 messages (pong)
__device__ u16 g_tmsgh[(size_t)M_N * HD];     // bf16 tree messages
__device__ u16 g_P[(size_t)POOL_N * HD];      // P = pool @ W_h   (bf16)
__device__ u16 g_Q[(size_t)POOL_N * HD];      // Q = pool @ Wo[35:291] (bf16)
__device__ u16 g_binH[(size_t)B_N * HD];      // bf16 binput
__device__ float g_F[(size_t)A_N * HD];       // fp32 fatoms@Wo_top + bias
// packed split-bf16 weights in MFMA A-fragment order: [(c*16+t)*64+lane]*8+j
__device__ u16 g_pWh_hi[65536], g_pWh_lo[65536];
__device__ u16 g_pWo_hi[65536], g_pWo_lo[65536];
__device__ float g_counts[N_MOLS];

__device__ __forceinline__ u16 f2b(float f)
{
    union { float f; unsigned u; } x; x.f = f;
    const unsigned r = x.u + 0x7FFFu + ((x.u >> 16) & 1u);
    return (u16)(r >> 16);
}
__device__ __forceinline__ float b2f(u16 h) { return __uint_as_float((unsigned)h << 16); }
__device__ __forceinline__ float blo(unsigned u) { return __uint_as_float(u << 16); }
__device__ __forceinline__ float bhi(unsigned u) { return __uint_as_float(u & 0xffff0000u); }

// ---------------- setup kernels ----------------
__global__ __launch_bounds__(256)
void k_zero_out(float* __restrict__ p, int n)
{
    const int i = blockIdx.x * 256 + threadIdx.x;
    if (i < n) p[i] = 0.f;
}

__global__ __launch_bounds__(256)
void k_zero_counts()
{
    const int i = blockIdx.x * 256 + threadIdx.x;
    if (i < N_MOLS) g_counts[i] = 0.f;
}

__global__ __launch_bounds__(256)
void k_cvt(const float* __restrict__ tmsg)
{
    const int i = (blockIdx.x * 256 + threadIdx.x) * 4;
    if (i < M_N * HD) {
        const float4 v = *(const float4*)(tmsg + i);
        ushort4 o;
        o.x = f2b(v.x); o.y = f2b(v.y); o.z = f2b(v.z); o.w = f2b(v.w);
        *(ushort4*)(g_tmsgh + i) = o;
    }
}

// pack Wh and Wo[35:291] into split-bf16 MFMA A-fragment layout.
//   packed[((c*16+t)*64+lane)*8+j] = W[c*32+(lane>>4)*8+j][t*16+(lane&15)]
__global__ __launch_bounds__(256)
void k_packW(const float* __restrict__ Wh, const float* __restrict__ Wo)
{
    const int id = blockIdx.x * 256 + threadIdx.x;   // 0..8191
    if (id >= 8192) return;
    const int l = id & 63;
    const int t = (id >> 6) & 15;
    const int c = id >> 10;
    const int n = t * 16 + (l & 15);
    const int kb = c * 32 + ((l >> 4) << 3);
    const size_t base = (size_t)id * 8;
    #pragma unroll
    for (int j = 0; j < 8; ++j) {
        const int k = kb + j;
        const float wh = Wh[(size_t)k * HD + n];
        const u16 hh = f2b(wh);
        g_pWh_hi[base + j] = hh;
        g_pWh_lo[base + j] = f2b(wh - b2f(hh));
        const float wo = Wo[(size_t)(35 + k) * HD + n];
        const u16 oh = f2b(wo);
        g_pWo_hi[base + j] = oh;
        g_pWo_lo[base + j] = f2b(wo - b2f(oh));
    }
}

// ---------------- K1: binH = bf16(fbonds @ W_i); msg0 = bf16(relu(binput)) ----------------
// R12: the old version re-read W_i from LDS for EVERY row: 40 ds_read_b128/row
// = ~480 cyc of LDS-unit occupancy per row (~150 us/kernel, 4x memory floor).
// Each lane only ever uses 4 columns of W_i -> hold them in 160 VGPRs, loaded
// once per wave. Row features are wave-uniform broadcast loads (1 line each).
// __launch_bounds__(256,2) caps at 256 VGPR (no spill at ~200 used);
// persistent grid (512 blocks = 2/CU) so the weight preload happens once.
__global__ __launch_bounds__(256, 2)
void k_in(const float* __restrict__ fbonds, const float* __restrict__ Wi)
{
    const int lane = threadIdx.x & 63;
    const int wid  = (blockIdx.x * 256 + threadIdx.x) >> 6;
    const int nw   = (gridDim.x * 256) >> 6;

    float4 w[FB_DIM];                                  // 160 VGPR: W_i[:, lane*4..+4)
    #pragma unroll
    for (int k = 0; k < FB_DIM; ++k)
        w[k] = *(const float4*)&Wi[(size_t)k * HD + lane * 4];

    #pragma unroll 1
    for (int row = wid; row < B_N; row += nw) {
        const float* fr = fbonds + (size_t)row * FB_DIM;
        float ax = 0.f, ay = 0.f, az = 0.f, aw = 0.f;
        #pragma unroll
        for (int q = 0; q < FB_DIM / 4; ++q) {
            const float4 fv = *(const float4*)(fr + q * 4);
            ax += fv.x * w[q*4+0].x; ay += fv.x * w[q*4+0].y;
            az += fv.x * w[q*4+0].z; aw += fv.x * w[q*4+0].w;
            ax += fv.y * w[q*4+1].x; ay += fv.y * w[q*4+1].y;
            az += fv.y * w[q*4+1].z; aw += fv.y * w[q*4+1].w;
            ax += fv.z * w[q*4+2].x; ay += fv.z * w[q*4+2].y;
            az += fv.z * w[q*4+2].z; aw += fv.z * w[q*4+2].w;
            ax += fv.w * w[q*4+3].x; ay += fv.w * w[q*4+3].y;
            az += fv.w * w[q*4+3].z; aw += fv.w * w[q*4+3].w;
        }
        const size_t base = (size_t)row * HD + lane * 4;
        ushort4 bi;
        bi.x = f2b(ax); bi.y = f2b(ay); bi.z = f2b(az); bi.w = f2b(aw);
        *(ushort4*)(g_binH + base) = bi;
        ushort4 o;
        o.x = f2b(fmaxf(ax, 0.f)); o.y = f2b(fmaxf(ay, 0.f));
        o.z = f2b(fmaxf(az, 0.f)); o.w = f2b(fmaxf(aw, 0.f));
        *(ushort4*)(g_msg0 + base) = o;
    }
}

// ------- K2: MFMA GEMM — dst[row] = bf16(pool[row] @ W) with split-bf16 W -------
// R11: wave tile = 64 rows x 128 cols (block = 128 rows x 256 cols): each ah/al
// fragment feeds 4 MFMAs. acc[4][8] f32x4 = 128 VGPR; all rg/t indexing is
// compile-time static (only the c-loop is a runtime loop; acc never indexed by
// c) so nothing spills to scratch (the R10 trap).
__global__ __launch_bounds__(256, 2)
void k_gemmMF(int sel, int rowStart, int rowEnd)
{
    const u16* msrc = (sel == 1) ? g_msg1 : g_msg0;
    const u16* pHi  = (sel == 2) ? g_pWo_hi : g_pWh_hi;
    const u16* pLo  = (sel == 2) ? g_pWo_lo : g_pWh_lo;
    u16* dst        = (sel == 2) ? g_Q : g_P;

    const int tid  = threadIdx.x;
    const int lane = tid & 63;
    const int wv   = tid >> 6;            // 0..3
    const int l15  = lane & 15;
    const int quad = lane >> 4;
    const int tOff = (wv & 1) * 8;        // col-half: tiles [tOff, tOff+8)

    // 4 row-groups of 16 rows each: wave covers 64 rows x 128 cols.
    int rowIdeal[4];
    const u16* srow[4];
    #pragma unroll
    for (int rg = 0; rg < 4; ++rg) {
        const int ri = rowStart + blockIdx.x * 128 + (wv >> 1) * 64 + rg * 16 + l15;
        rowIdeal[rg] = ri;
        const int r = (ri < rowEnd) ? ri : (rowEnd - 1);
        srow[rg] = (r < M_N) ? (g_tmsgh + (size_t)r * HD)
                             : (msrc + (size_t)(r - M_N) * HD);
    }

    f32x4 acc[4][8];
    #pragma unroll
    for (int rg = 0; rg < 4; ++rg)
        #pragma unroll
        for (int t = 0; t < 8; ++t)
            acc[rg][t] = (f32x4){0.f, 0.f, 0.f, 0.f};

    #pragma unroll 1
    for (int c = 0; c < 8; ++c) {
        bf16x8 b[4];
        #pragma unroll
        for (int rg = 0; rg < 4; ++rg)
            b[rg] = *(const bf16x8*)(srow[rg] + c * 32 + quad * 8);
        const u16* ph = pHi + ((size_t)(c * 16 + tOff) * 64 + lane) * 8;
        const u16* pl = pLo + ((size_t)(c * 16 + tOff) * 64 + lane) * 8;
        #pragma unroll
        for (int t = 0; t < 8; ++t) {
            const bf16x8 ah = *(const bf16x8*)(ph + (size_t)t * 512);
            #pragma unroll
            for (int rg = 0; rg < 4; ++rg)
                acc[rg][t] = __builtin_amdgcn_mfma_f32_16x16x32_bf16(ah, b[rg], acc[rg][t], 0, 0, 0);
            const bf16x8 al = *(const bf16x8*)(pl + (size_t)t * 512);
            #pragma unroll
            for (int rg = 0; rg < 4; ++rg)
                acc[rg][t] = __builtin_amdgcn_mfma_f32_16x16x32_bf16(al, b[rg], acc[rg][t], 0, 0, 0);
        }
    }

    #pragma unroll
    for (int rg = 0; rg < 4; ++rg) {
        if (rowIdeal[rg] < rowEnd) {
            u16* drow = dst + (size_t)rowIdeal[rg] * HD + tOff * 16 + quad * 4;
            #pragma unroll
            for (int t = 0; t < 8; ++t) {
                ushort4 o;
                o.x = f2b(acc[rg][t][0]); o.y = f2b(acc[rg][t][1]);
                o.z = f2b(acc[rg][t][2]); o.w = f2b(acc[rg][t][3]);
                *(ushort4*)(drow + t * 16) = o;
            }
        }
    }
}

// ------- K3: dst = bf16(relu(binH + sum_j P[bgraph[r][j]])) — pure gather -------
__global__ __launch_bounds__(256)
void k_gather(const int* __restrict__ bgraph, int dstSel)
{
    u16* dst = dstSel ? g_msg1 : g_msg0;
    __shared__ int idx_s[8][MAX_NB];
    const int tid = threadIdx.x;
    const int rowBase = blockIdx.x * 8;
    if (tid < 8 * MAX_NB) {
        const int r = tid / MAX_NB;
        const int j = tid - r * MAX_NB;
        idx_s[r][j] = bgraph[(size_t)(rowBase + r) * MAX_NB + j];
    }
    __syncthreads();
    const int rl = tid >> 5;           // [0,8)
    const int c  = (tid & 31) << 3;    // 8 bf16 = 16 B per thread
    const int row = rowBase + rl;

    float s[8] = {0.f,0.f,0.f,0.f,0.f,0.f,0.f,0.f};
    #pragma unroll
    for (int j = 0; j < MAX_NB; ++j) {
        const uint4 v = *(const uint4*)(g_P + (size_t)idx_s[rl][j] * HD + c);
        s[0] += blo(v.x); s[1] += bhi(v.x);
        s[2] += blo(v.y); s[3] += bhi(v.y);
        s[4] += blo(v.z); s[5] += bhi(v.z);
        s[6] += blo(v.w); s[7] += bhi(v.w);
    }
    const uint4 bv = *(const uint4*)(g_binH + (size_t)row * HD + c);
    uint4 w;
    w.x = ((unsigned)f2b(fmaxf(s[0] + blo(bv.x), 0.f)))
        | ((unsigned)f2b(fmaxf(s[1] + bhi(bv.x), 0.f)) << 16);
    w.y = ((unsigned)f2b(fmaxf(s[2] + blo(bv.y), 0.f)))
        | ((unsigned)f2b(fmaxf(s[3] + bhi(bv.y), 0.f)) << 16);
    w.z = ((unsigned)f2b(fmaxf(s[4] + blo(bv.z), 0.f)))
        | ((unsigned)f2b(fmaxf(s[5] + bhi(bv.z), 0.f)) << 16);
    w.w = ((unsigned)f2b(fmaxf(s[6] + blo(bv.w), 0.f)))
        | ((unsigned)f2b(fmaxf(s[7] + bhi(bv.w), 0.f)) << 16);
    *(uint4*)(dst + (size_t)row * HD + c) = w;
}

// ------- K4: F = fatoms @ Wo[0:35] + bias (fp32) -------
// R12: same register-resident-weight rewrite as k_in (35 float4 = 140 VGPR,
// loaded once per wave; no LDS).
__global__ __launch_bounds__(256, 2)
void k_F(const float* __restrict__ fatoms, const float* __restrict__ Wo,
         const float* __restrict__ bias)
{
    const int lane = threadIdx.x & 63;
    const int wid  = (blockIdx.x * 256 + threadIdx.x) >> 6;
    const int nw   = (gridDim.x * 256) >> 6;

    float4 w[ATOM_FDIM];                               // 140 VGPR
    #pragma unroll
    for (int k = 0; k < ATOM_FDIM; ++k)
        w[k] = *(const float4*)&Wo[(size_t)k * HD + lane * 4];
    const float4 b4 = *(const float4*)&bias[lane * 4];

    #pragma unroll 1
    for (int row = wid; row < A_N; row += nw) {
        const float* fr = fatoms + (size_t)row * ATOM_FDIM;
        float ax = b4.x, ay = b4.y, az = b4.z, aw = b4.w;
        #pragma unroll
        for (int k = 0; k < ATOM_FDIM; ++k) {
            const float f = fr[k];
            ax += f * w[k].x; ay += f * w[k].y;
            az += f * w[k].z; aw += f * w[k].w;
        }
        float4 o; o.x = ax; o.y = ay; o.z = az; o.w = aw;
        *(float4*)(g_F + (size_t)row * HD + lane * 4) = o;
    }
}

// ------- K5: out[mol] += relu(F[a] + sum_j Q[agraph[a][j]]) — gather + segsum -------
__global__ __launch_bounds__(256)
void k_gatherA(const int* __restrict__ agraph, const int* __restrict__ scope,
               float* __restrict__ out)
{
    __shared__ int idx_s[64 * MAX_NB];
    __shared__ int sc_s[64];
    const int tid = threadIdx.x;
    const int rb = blockIdx.x * 64;
    for (int i = tid; i < 64 * MAX_NB; i += 256) {
        const int a = rb + i / MAX_NB;
        idx_s[i] = (a < A_N) ? agraph[(size_t)a * MAX_NB + (i % MAX_NB)] : 0;
    }
    if (tid < 64) sc_s[tid] = (rb + tid < A_N) ? scope[rb + tid] : -1;
    __syncthreads();

    const int grp = tid >> 5;          // 8 atoms per group, processed sequentially
    const int c = (tid & 31) * 8;      // 8 cols per thread
    float s[8] = {0.f,0.f,0.f,0.f,0.f,0.f,0.f,0.f};
    int prev = -1;
    #pragma unroll 1
    for (int i = 0; i < 8; ++i) {
        const int al = grp * 8 + i;
        const int a = rb + al;
        if (a < A_N) {
            const int m = sc_s[al];
            if (m != prev) {
                if (prev >= 0) {
                    float* dst = out + (size_t)prev * HD + c;
                    #pragma unroll
                    for (int q = 0; q < 8; ++q) atomicAdd(dst + q, s[q]);
                    #pragma unroll
                    for (int q = 0; q < 8; ++q) s[q] = 0.f;
                }
                prev = m;
            }
            float g0=0.f,g1=0.f,g2=0.f,g3=0.f,g4=0.f,g5=0.f,g6=0.f,g7=0.f;
            #pragma unroll
            for (int j = 0; j < MAX_NB; ++j) {
                const uint4 v = *(const uint4*)(g_Q + (size_t)idx_s[al * MAX_NB + j] * HD + c);
                g0 += blo(v.x); g1 += bhi(v.x);
                g2 += blo(v.y); g3 += bhi(v.y);
                g4 += blo(v.z); g5 += bhi(v.z);
                g6 += blo(v.w); g7 += bhi(v.w);
            }
            const float4 f0 = *(const float4*)(g_F + (size_t)a * HD + c);
            const float4 f1 = *(const float4*)(g_F + (size_t)a * HD + c + 4);
            s[0] += fmaxf(g0 + f0.x, 0.f); s[1] += fmaxf(g1 + f0.y, 0.f);
            s[2] += fmaxf(g2 + f0.z, 0.f); s[3] += fmaxf(g3 + f0.w, 0.f);
            s[4] += fmaxf(g4 + f1.x, 0.f); s[5] += fmaxf(g5 + f1.y, 0.f);
            s[6] += fmaxf(g6 + f1.z, 0.f); s[7] += fmaxf(g7 + f1.w, 0.f);
        }
    }
    if (prev >= 0) {
        float* dst = out + (size_t)prev * HD + c;
        #pragma unroll
        for (int q = 0; q < 8; ++q) atomicAdd(dst + q, s[q]);
    }
}

// ---------------- counts + divide ----------------
__global__ __launch_bounds__(256)
void k_counts(const int* __restrict__ scope)
{
    const int a = blockIdx.x * 256 + threadIdx.x;
    if (a < A_N) atomicAdd(&g_counts[scope[a]], 1.0f);
}

__global__ __launch_bounds__(256)
void k_div(float* __restrict__ out)
{
    const int idx = blockIdx.x * 256 + threadIdx.x;
    out[idx] = out[idx] / fmaxf(g_counts[idx >> 8], 1.0f);
}

// ---------------- launch ----------------
extern "C" void kernel_launch(void* const* d_in, const int* in_sizes, int n_in,
                              void* d_out, int out_size, void* d_ws, size_t ws_size,
                              hipStream_t stream)
{
    const float* fatoms = (const float*)d_in[0];
    const float* fbonds = (const float*)d_in[1];
    const int*   agraph = (const int*)d_in[2];
    const int*   bgraph = (const int*)d_in[3];
    const float* tmsg   = (const float*)d_in[4];
    const int*   scope  = (const int*)d_in[5];
    const float* W_i    = (const float*)d_in[6];
    const float* W_h    = (const float*)d_in[7];
    const float* W_o    = (const float*)d_in[8];
    const float* W_ob   = (const float*)d_in[9];
    float* out = (float*)d_out;

    (void)d_ws; (void)ws_size;

    k_zero_out<<<(N_MOLS * HD + 255) / 256, 256, 0, stream>>>(out, N_MOLS * HD);
    k_zero_counts<<<(N_MOLS + 255) / 256, 256, 0, stream>>>();
    k_cvt<<<(M_N * HD / 4 + 255) / 256, 256, 0, stream>>>(tmsg);
    k_packW<<<32, 256, 0, stream>>>(W_h, W_o);

    k_in<<<512, 256, 0, stream>>>(fbonds, W_i);             // binH + msg0 (persistent)

    // iter 0: P = [tmsg; msg0] @ Wh; msg1 = relu(binH + gatherP)
    k_gemmMF<<<(POOL_N + 127) / 128, 256, 0, stream>>>(0, 0, POOL_N);
    k_gather<<<B_N / 8, 256, 0, stream>>>(bgraph, 1);
    // iter 1: only msg rows of P change
    k_gemmMF<<<(B_N + 127) / 128, 256, 0, stream>>>(1, M_N, POOL_N);
    k_gather<<<B_N / 8, 256, 0, stream>>>(bgraph, 0);

    // readout: Q = [tmsg; msg0] @ Wo[35:291]; F = fatoms@Wo[0:35]+b; gather+segsum
    k_gemmMF<<<(POOL_N + 127) / 128, 256, 0, stream>>>(2, 0, POOL_N);
    k_F<<<512, 256, 0, stream>>>(fatoms, W_o, W_ob);
    k_counts<<<(A_N + 255) / 256, 256, 0, stream>>>(scope);
    k_gatherA<<<(A_N + 63) / 64, 256, 0, stream>>>(agraph, scope, out);
    k_div<<<(N_MOLS * HD) / 256, 256, 0, stream>>>(out);
}

// Round 3
// 1288.228 us; speedup vs baseline: 1.1547x; 1.0168x over previous
//
#include <hip/hip_runtime.h>
#include <cstdint>
#include <cstddef>

#define A_N 100000
#define B_N 200000
#define M_N 20000
#define POOL_N 220000   // M_N + B_N
#define HD 256
#define MAX_NB 10
#define N_MOLS 2000
#define ATOM_FDIM 35
#define FB_DIM 40

typedef unsigned short u16;
typedef __attribute__((ext_vector_type(8))) short bf16x8;
typedef __attribute__((ext_vector_type(4))) float f32x4;

// Static device buffers (BSS).
__device__ u16 g_msg0[(size_t)B_N * HD];      // bf16 messages (ping)
__device__ u16 g_msg1[(size_t)B_N * HD];      // bf16 messages (pong)
__device__ u16 g_tmsgh[(size_t)M_N * HD];     // bf16 tree messages
__device__ u16 g_P[(size_t)POOL_N * HD];      // P = pool @ W_h   (bf16)
__device__ u16 g_Q[(size_t)POOL_N * HD];      // Q = pool @ Wo[35:291] (bf16)
__device__ u16 g_binH[(size_t)B_N * HD];      // bf16 binput
__device__ u16 g_Fh[(size_t)A_N * HD];        // bf16 fatoms@Wo_top + bias (R13: was fp32)
// packed split-bf16 weights in MFMA A-fragment order: [(c*16+t)*64+lane]*8+j
__device__ u16 g_pWh_hi[65536], g_pWh_lo[65536];
__device__ u16 g_pWo_hi[65536], g_pWo_lo[65536];
__device__ float g_counts[N_MOLS];

__device__ __forceinline__ u16 f2b(float f)
{
    union { float f; unsigned u; } x; x.f = f;
    const unsigned r = x.u + 0x7FFFu + ((x.u >> 16) & 1u);
    return (u16)(r >> 16);
}
__device__ __forceinline__ float b2f(u16 h) { return __uint_as_float((unsigned)h << 16); }
__device__ __forceinline__ float blo(unsigned u) { return __uint_as_float(u << 16); }
__device__ __forceinline__ float bhi(unsigned u) { return __uint_as_float(u & 0xffff0000u); }

__device__ __forceinline__ int lbound(const int* __restrict__ s, int n, int v)
{
    int l = 0, r = n;
    while (l < r) { const int mid = (l + r) >> 1; if (s[mid] < v) l = mid + 1; else r = mid; }
    return l;
}

// ---------------- K0: fused setup ----------------
// R13: merges zero_out + cvt(tmsg->bf16) + packW + counts into one kernel.
// counts via binary search on the SORTED scope array (no atomics, no pre-zero).
// Segments by blockIdx: [0,2000) zero d_out; [2000,7000) cvt; [7000,7032) packW;
// [7032,7040) counts.
__global__ __launch_bounds__(256)
void k_setup(float* __restrict__ out, const float* __restrict__ tmsg,
             const float* __restrict__ Wh, const float* __restrict__ Wo,
             const int* __restrict__ scope)
{
    const int bid = blockIdx.x;
    const int tid = threadIdx.x;
    if (bid < 2000) {                       // zero d_out (N_MOLS*HD floats)
        out[bid * 256 + tid] = 0.f;
    } else if (bid < 7000) {                // cvt tree messages to bf16
        const int i = ((bid - 2000) * 256 + tid) * 4;
        if (i < M_N * HD) {
            const float4 v = *(const float4*)(tmsg + i);
            ushort4 o;
            o.x = f2b(v.x); o.y = f2b(v.y); o.z = f2b(v.z); o.w = f2b(v.w);
            *(ushort4*)(g_tmsgh + i) = o;
        }
    } else if (bid < 7032) {                // packW: split-bf16 MFMA fragments
        const int id = (bid - 7000) * 256 + tid;   // 0..8191
        const int l = id & 63;
        const int t = (id >> 6) & 15;
        const int c = id >> 10;
        const int n = t * 16 + (l & 15);
        const int kb = c * 32 + ((l >> 4) << 3);
        const size_t base = (size_t)id * 8;
        #pragma unroll
        for (int j = 0; j < 8; ++j) {
            const int k = kb + j;
            const float wh = Wh[(size_t)k * HD + n];
            const u16 hh = f2b(wh);
            g_pWh_hi[base + j] = hh;
            g_pWh_lo[base + j] = f2b(wh - b2f(hh));
            const float wo = Wo[(size_t)(35 + k) * HD + n];
            const u16 oh = f2b(wo);
            g_pWo_hi[base + j] = oh;
            g_pWo_lo[base + j] = f2b(wo - b2f(oh));
        }
    } else {                                // counts via binary search (scope sorted)
        const int m = (bid - 7032) * 256 + tid;
        if (m < N_MOLS) {
            const int lo = lbound(scope, A_N, m);
            const int hi = lbound(scope, A_N, m + 1);
            g_counts[m] = (float)(hi - lo);
        }
    }
}

// ---------------- K1: binH = bf16(fbonds @ W_i); msg0 = bf16(relu(binput)) ----------------
// R12: W_i columns held in 160 VGPRs per lane (loaded once per persistent wave);
// row features are wave-uniform broadcast loads.
__global__ __launch_bounds__(256, 2)
void k_in(const float* __restrict__ fbonds, const float* __restrict__ Wi)
{
    const int lane = threadIdx.x & 63;
    const int wid  = (blockIdx.x * 256 + threadIdx.x) >> 6;
    const int nw   = (gridDim.x * 256) >> 6;

    float4 w[FB_DIM];                                  // 160 VGPR: W_i[:, lane*4..+4)
    #pragma unroll
    for (int k = 0; k < FB_DIM; ++k)
        w[k] = *(const float4*)&Wi[(size_t)k * HD + lane * 4];

    #pragma unroll 1
    for (int row = wid; row < B_N; row += nw) {
        const float* fr = fbonds + (size_t)row * FB_DIM;
        float ax = 0.f, ay = 0.f, az = 0.f, aw = 0.f;
        #pragma unroll
        for (int q = 0; q < FB_DIM / 4; ++q) {
            const float4 fv = *(const float4*)(fr + q * 4);
            ax += fv.x * w[q*4+0].x; ay += fv.x * w[q*4+0].y;
            az += fv.x * w[q*4+0].z; aw += fv.x * w[q*4+0].w;
            ax += fv.y * w[q*4+1].x; ay += fv.y * w[q*4+1].y;
            az += fv.y * w[q*4+1].z; aw += fv.y * w[q*4+1].w;
            ax += fv.z * w[q*4+2].x; ay += fv.z * w[q*4+2].y;
            az += fv.z * w[q*4+2].z; aw += fv.z * w[q*4+2].w;
            ax += fv.w * w[q*4+3].x; ay += fv.w * w[q*4+3].y;
            az += fv.w * w[q*4+3].z; aw += fv.w * w[q*4+3].w;
        }
        const size_t base = (size_t)row * HD + lane * 4;
        ushort4 bi;
        bi.x = f2b(ax); bi.y = f2b(ay); bi.z = f2b(az); bi.w = f2b(aw);
        *(ushort4*)(g_binH + base) = bi;
        ushort4 o;
        o.x = f2b(fmaxf(ax, 0.f)); o.y = f2b(fmaxf(ay, 0.f));
        o.z = f2b(fmaxf(az, 0.f)); o.w = f2b(fmaxf(aw, 0.f));
        *(ushort4*)(g_msg0 + base) = o;
    }
}

// ------- K2: MFMA GEMM — dst[row] = bf16(pool[row] @ W) with split-bf16 W -------
// R11: wave tile 64 rows x 128 cols; acc[4][8] static.  R13: manual prefetch of
// the next c-iteration's 4 HBM B-fragments into named registers (T14 issue-early
// pattern) so their ~600-900 cyc latency hides under this iteration's 64 MFMAs.
__global__ __launch_bounds__(256, 2)
void k_gemmMF(int sel, int rowStart, int rowEnd)
{
    const u16* msrc = (sel == 1) ? g_msg1 : g_msg0;
    const u16* pHi  = (sel == 2) ? g_pWo_hi : g_pWh_hi;
    const u16* pLo  = (sel == 2) ? g_pWo_lo : g_pWh_lo;
    u16* dst        = (sel == 2) ? g_Q : g_P;

    const int tid  = threadIdx.x;
    const int lane = tid & 63;
    const int wv   = tid >> 6;            // 0..3
    const int l15  = lane & 15;
    const int quad = lane >> 4;
    const int tOff = (wv & 1) * 8;        // col-half: tiles [tOff, tOff+8)

    int rowIdeal[4];
    const u16* srow[4];
    #pragma unroll
    for (int rg = 0; rg < 4; ++rg) {
        const int ri = rowStart + blockIdx.x * 128 + (wv >> 1) * 64 + rg * 16 + l15;
        rowIdeal[rg] = ri;
        const int r = (ri < rowEnd) ? ri : (rowEnd - 1);
        srow[rg] = (r < M_N) ? (g_tmsgh + (size_t)r * HD)
                             : (msrc + (size_t)(r - M_N) * HD);
    }

    f32x4 acc[4][8];
    #pragma unroll
    for (int rg = 0; rg < 4; ++rg)
        #pragma unroll
        for (int t = 0; t < 8; ++t)
            acc[rg][t] = (f32x4){0.f, 0.f, 0.f, 0.f};

    bf16x8 b0 = *(const bf16x8*)(srow[0] + quad * 8);
    bf16x8 b1 = *(const bf16x8*)(srow[1] + quad * 8);
    bf16x8 b2 = *(const bf16x8*)(srow[2] + quad * 8);
    bf16x8 b3 = *(const bf16x8*)(srow[3] + quad * 8);

    #pragma unroll 1
    for (int c = 0; c < 8; ++c) {
        const int cn = (c + 1) & 7;        // wrap: iter 7 re-reads c=0 (harmless)
        const bf16x8 n0 = *(const bf16x8*)(srow[0] + cn * 32 + quad * 8);
        const bf16x8 n1 = *(const bf16x8*)(srow[1] + cn * 32 + quad * 8);
        const bf16x8 n2 = *(const bf16x8*)(srow[2] + cn * 32 + quad * 8);
        const bf16x8 n3 = *(const bf16x8*)(srow[3] + cn * 32 + quad * 8);
        const u16* ph = pHi + ((size_t)(c * 16 + tOff) * 64 + lane) * 8;
        const u16* pl = pLo + ((size_t)(c * 16 + tOff) * 64 + lane) * 8;
        #pragma unroll
        for (int t = 0; t < 8; ++t) {
            const bf16x8 ah = *(const bf16x8*)(ph + (size_t)t * 512);
            acc[0][t] = __builtin_amdgcn_mfma_f32_16x16x32_bf16(ah, b0, acc[0][t], 0, 0, 0);
            acc[1][t] = __builtin_amdgcn_mfma_f32_16x16x32_bf16(ah, b1, acc[1][t], 0, 0, 0);
            acc[2][t] = __builtin_amdgcn_mfma_f32_16x16x32_bf16(ah, b2, acc[2][t], 0, 0, 0);
            acc[3][t] = __builtin_amdgcn_mfma_f32_16x16x32_bf16(ah, b3, acc[3][t], 0, 0, 0);
            const bf16x8 al = *(const bf16x8*)(pl + (size_t)t * 512);
            acc[0][t] = __builtin_amdgcn_mfma_f32_16x16x32_bf16(al, b0, acc[0][t], 0, 0, 0);
            acc[1][t] = __builtin_amdgcn_mfma_f32_16x16x32_bf16(al, b1, acc[1][t], 0, 0, 0);
            acc[2][t] = __builtin_amdgcn_mfma_f32_16x16x32_bf16(al, b2, acc[2][t], 0, 0, 0);
            acc[3][t] = __builtin_amdgcn_mfma_f32_16x16x32_bf16(al, b3, acc[3][t], 0, 0, 0);
        }
        b0 = n0; b1 = n1; b2 = n2; b3 = n3;
    }

    #pragma unroll
    for (int rg = 0; rg < 4; ++rg) {
        if (rowIdeal[rg] < rowEnd) {
            u16* drow = dst + (size_t)rowIdeal[rg] * HD + tOff * 16 + quad * 4;
            #pragma unroll
            for (int t = 0; t < 8; ++t) {
                ushort4 o;
                o.x = f2b(acc[rg][t][0]); o.y = f2b(acc[rg][t][1]);
                o.z = f2b(acc[rg][t][2]); o.w = f2b(acc[rg][t][3]);
                *(ushort4*)(drow + t * 16) = o;
            }
        }
    }
}

// ------- K3: dst = bf16(relu(binH + sum_j P[bgraph[r][j]])) — pure gather -------
// R13: row-chunked (rowOff) so each dispatch is ~1/4 -> surfaces other kernels
// in the top-5 profile. Access pattern unchanged. binH load issued early.
__global__ __launch_bounds__(256)
void k_gather(const int* __restrict__ bgraph, int dstSel, int rowOff)
{
    u16* dst = dstSel ? g_msg1 : g_msg0;
    __shared__ int idx_s[8][MAX_NB];
    const int tid = threadIdx.x;
    const int rowBase = rowOff + blockIdx.x * 8;
    if (tid < 8 * MAX_NB) {
        const int r = tid / MAX_NB;
        const int j = tid - r * MAX_NB;
        idx_s[r][j] = bgraph[(size_t)(rowBase + r) * MAX_NB + j];
    }
    __syncthreads();
    const int rl = tid >> 5;           // [0,8)
    const int c  = (tid & 31) << 3;    // 8 bf16 = 16 B per thread
    const int row = rowBase + rl;

    const uint4 bv = *(const uint4*)(g_binH + (size_t)row * HD + c);
    float s[8] = {0.f,0.f,0.f,0.f,0.f,0.f,0.f,0.f};
    #pragma unroll
    for (int j = 0; j < MAX_NB; ++j) {
        const uint4 v = *(const uint4*)(g_P + (size_t)idx_s[rl][j] * HD + c);
        s[0] += blo(v.x); s[1] += bhi(v.x);
        s[2] += blo(v.y); s[3] += bhi(v.y);
        s[4] += blo(v.z); s[5] += bhi(v.z);
        s[6] += blo(v.w); s[7] += bhi(v.w);
    }
    uint4 w;
    w.x = ((unsigned)f2b(fmaxf(s[0] + blo(bv.x), 0.f)))
        | ((unsigned)f2b(fmaxf(s[1] + bhi(bv.x), 0.f)) << 16);
    w.y = ((unsigned)f2b(fmaxf(s[2] + blo(bv.y), 0.f)))
        | ((unsigned)f2b(fmaxf(s[3] + bhi(bv.y), 0.f)) << 16);
    w.z = ((unsigned)f2b(fmaxf(s[4] + blo(bv.z), 0.f)))
        | ((unsigned)f2b(fmaxf(s[5] + bhi(bv.z), 0.f)) << 16);
    w.w = ((unsigned)f2b(fmaxf(s[6] + blo(bv.w), 0.f)))
        | ((unsigned)f2b(fmaxf(s[7] + bhi(bv.w), 0.f)) << 16);
    *(uint4*)(dst + (size_t)row * HD + c) = w;
}

// ------- K4: Fh = bf16(fatoms @ Wo[0:35] + bias) -------
// R12: register-resident weights. R13: bf16 output (halves F traffic here and
// in gatherA; same precision treatment as binH).
__global__ __launch_bounds__(256, 2)
void k_F(const float* __restrict__ fatoms, const float* __restrict__ Wo,
         const float* __restrict__ bias)
{
    const int lane = threadIdx.x & 63;
    const int wid  = (blockIdx.x * 256 + threadIdx.x) >> 6;
    const int nw   = (gridDim.x * 256) >> 6;

    float4 w[ATOM_FDIM];                               // 140 VGPR
    #pragma unroll
    for (int k = 0; k < ATOM_FDIM; ++k)
        w[k] = *(const float4*)&Wo[(size_t)k * HD + lane * 4];
    const float4 b4 = *(const float4*)&bias[lane * 4];

    #pragma unroll 1
    for (int row = wid; row < A_N; row += nw) {
        const float* fr = fatoms + (size_t)row * ATOM_FDIM;
        float ax = b4.x, ay = b4.y, az = b4.z, aw = b4.w;
        #pragma unroll
        for (int k = 0; k < ATOM_FDIM; ++k) {
            const float f = fr[k];
            ax += f * w[k].x; ay += f * w[k].y;
            az += f * w[k].z; aw += f * w[k].w;
        }
        ushort4 o;
        o.x = f2b(ax); o.y = f2b(ay); o.z = f2b(az); o.w = f2b(aw);
        *(ushort4*)(g_Fh + (size_t)row * HD + lane * 4) = o;
    }
}

// ------- K5: out[mol] += relu(F[a] + sum_j Q[agraph[a][j]]) — gather + segsum -------
__global__ __launch_bounds__(256)
void k_gatherA(const int* __restrict__ agraph, const int* __restrict__ scope,
               float* __restrict__ out)
{
    __shared__ int idx_s[64 * MAX_NB];
    __shared__ int sc_s[64];
    const int tid = threadIdx.x;
    const int rb = blockIdx.x * 64;
    for (int i = tid; i < 64 * MAX_NB; i += 256) {
        const int a = rb + i / MAX_NB;
        idx_s[i] = (a < A_N) ? agraph[(size_t)a * MAX_NB + (i % MAX_NB)] : 0;
    }
    if (tid < 64) sc_s[tid] = (rb + tid < A_N) ? scope[rb + tid] : -1;
    __syncthreads();

    const int grp = tid >> 5;          // 8 atoms per group, processed sequentially
    const int c = (tid & 31) * 8;      // 8 cols per thread
    float s[8] = {0.f,0.f,0.f,0.f,0.f,0.f,0.f,0.f};
    int prev = -1;
    #pragma unroll 1
    for (int i = 0; i < 8; ++i) {
        const int al = grp * 8 + i;
        const int a = rb + al;
        if (a < A_N) {
            const int m = sc_s[al];
            if (m != prev) {
                if (prev >= 0) {
                    float* dst = out + (size_t)prev * HD + c;
                    #pragma unroll
                    for (int q = 0; q < 8; ++q) atomicAdd(dst + q, s[q]);
                    #pragma unroll
                    for (int q = 0; q < 8; ++q) s[q] = 0.f;
                }
                prev = m;
            }
            const uint4 fv = *(const uint4*)(g_Fh + (size_t)a * HD + c);  // issue early
            float g0=0.f,g1=0.f,g2=0.f,g3=0.f,g4=0.f,g5=0.f,g6=0.f,g7=0.f;
            #pragma unroll
            for (int j = 0; j < MAX_NB; ++j) {
                const uint4 v = *(const uint4*)(g_Q + (size_t)idx_s[al * MAX_NB + j] * HD + c);
                g0 += blo(v.x); g1 += bhi(v.x);
                g2 += blo(v.y); g3 += bhi(v.y);
                g4 += blo(v.z); g5 += bhi(v.z);
                g6 += blo(v.w); g7 += bhi(v.w);
            }
            s[0] += fmaxf(g0 + blo(fv.x), 0.f); s[1] += fmaxf(g1 + bhi(fv.x), 0.f);
            s[2] += fmaxf(g2 + blo(fv.y), 0.f); s[3] += fmaxf(g3 + bhi(fv.y), 0.f);
            s[4] += fmaxf(g4 + blo(fv.z), 0.f); s[5] += fmaxf(g5 + bhi(fv.z), 0.f);
            s[6] += fmaxf(g6 + blo(fv.w), 0.f); s[7] += fmaxf(g7 + bhi(fv.w), 0.f);
        }
    }
    if (prev >= 0) {
        float* dst = out + (size_t)prev * HD + c;
        #pragma unroll
        for (int q = 0; q < 8; ++q) atomicAdd(dst + q, s[q]);
    }
}

// ---------------- divide ----------------
__global__ __launch_bounds__(256)
void k_div(float* __restrict__ out)
{
    const int idx = blockIdx.x * 256 + threadIdx.x;
    out[idx] = out[idx] / fmaxf(g_counts[idx >> 8], 1.0f);
}

// ---------------- launch ----------------
extern "C" void kernel_launch(void* const* d_in, const int* in_sizes, int n_in,
                              void* d_out, int out_size, void* d_ws, size_t ws_size,
                              hipStream_t stream)
{
    const float* fatoms = (const float*)d_in[0];
    const float* fbonds = (const float*)d_in[1];
    const int*   agraph = (const int*)d_in[2];
    const int*   bgraph = (const int*)d_in[3];
    const float* tmsg   = (const float*)d_in[4];
    const int*   scope  = (const int*)d_in[5];
    const float* W_i    = (const float*)d_in[6];
    const float* W_h    = (const float*)d_in[7];
    const float* W_o    = (const float*)d_in[8];
    const float* W_ob   = (const float*)d_in[9];
    float* out = (float*)d_out;

    (void)d_ws; (void)ws_size;

    k_setup<<<7040, 256, 0, stream>>>(out, tmsg, W_h, W_o, scope);
    k_in<<<512, 256, 0, stream>>>(fbonds, W_i);             // binH + msg0 (persistent)

    // iter 0: P = [tmsg; msg0] @ Wh; msg1 = relu(binH + gatherP)
    k_gemmMF<<<(POOL_N + 127) / 128, 256, 0, stream>>>(0, 0, POOL_N);
    for (int ch = 0; ch < 4; ++ch)
        k_gather<<<B_N / 32, 256, 0, stream>>>(bgraph, 1, ch * (B_N / 4));
    // iter 1: only msg rows of P change
    k_gemmMF<<<(B_N + 127) / 128, 256, 0, stream>>>(1, M_N, POOL_N);
    for (int ch = 0; ch < 4; ++ch)
        k_gather<<<B_N / 32, 256, 0, stream>>>(bgraph, 0, ch * (B_N / 4));

    // readout: Q = [tmsg; msg0] @ Wo[35:291]; Fh = fatoms@Wo[0:35]+b; gather+segsum
    k_gemmMF<<<(POOL_N + 127) / 128, 256, 0, stream>>>(2, 0, POOL_N);
    k_F<<<512, 256, 0, stream>>>(fatoms, W_o, W_ob);
    k_gatherA<<<(A_N + 63) / 64, 256, 0, stream>>>(agraph, scope, out);
    k_div<<<(N_MOLS * HD) / 256, 256, 0, stream>>>(out);
}

// Round 4
// 1199.880 us; speedup vs baseline: 1.2397x; 1.0736x over previous
//
#include <hip/hip_runtime.h>
#include <cstdint>
#include <cstddef>

#define A_N 100000
#define B_N 200000
#define M_N 20000
#define POOL_N 220000   // M_N + B_N
#define HD 256
#define MAX_NB 10
#define N_MOLS 2000
#define ATOM_FDIM 35
#define FB_DIM 40

typedef unsigned short u16;
typedef __attribute__((ext_vector_type(8))) short bf16x8;
typedef __attribute__((ext_vector_type(4))) float f32x4;

// Static device buffers (BSS).
__device__ u16 g_msg0[(size_t)B_N * HD];      // bf16 messages (ping)
__device__ u16 g_msg1[(size_t)B_N * HD];      // bf16 messages (pong)
__device__ u16 g_tmsgh[(size_t)M_N * HD];     // bf16 tree messages
__device__ u16 g_P[(size_t)POOL_N * HD];      // P = pool @ W_h   (bf16)
__device__ u16 g_Q[(size_t)POOL_N * HD];      // Q = pool @ Wo[35:291] (bf16)
__device__ u16 g_binH[(size_t)B_N * HD];      // bf16 binput
__device__ u16 g_Fh[(size_t)A_N * HD];        // bf16 fatoms@Wo_top + bias
// packed split-bf16 weights in MFMA A-fragment order: [(c*16+t)*64+lane]*8+j
__device__ u16 g_pWh_hi[65536], g_pWh_lo[65536];
__device__ u16 g_pWo_hi[65536], g_pWo_lo[65536];
__device__ int g_mstart[N_MOLS + 1];          // R14: molecule atom-range starts

__device__ __forceinline__ u16 f2b(float f)
{
    union { float f; unsigned u; } x; x.f = f;
    const unsigned r = x.u + 0x7FFFu + ((x.u >> 16) & 1u);
    return (u16)(r >> 16);
}
__device__ __forceinline__ float b2f(u16 h) { return __uint_as_float((unsigned)h << 16); }
__device__ __forceinline__ float blo(unsigned u) { return __uint_as_float(u << 16); }
__device__ __forceinline__ float bhi(unsigned u) { return __uint_as_float(u & 0xffff0000u); }

__device__ __forceinline__ int lbound(const int* __restrict__ s, int n, int v)
{
    int l = 0, r = n;
    while (l < r) { const int mid = (l + r) >> 1; if (s[mid] < v) l = mid + 1; else r = mid; }
    return l;
}

// ---------------- K0: fused setup ----------------
// Segments by blockIdx: [0,5000) cvt tmsg->bf16; [5000,5032) packW;
// [5032,5040) mstart (binary search on sorted scope; 2001 entries).
// R14: no out-zeroing (gatherA now overwrites out), counts -> mstart.
__global__ __launch_bounds__(256)
void k_setup(const float* __restrict__ tmsg,
             const float* __restrict__ Wh, const float* __restrict__ Wo,
             const int* __restrict__ scope)
{
    const int bid = blockIdx.x;
    const int tid = threadIdx.x;
    if (bid < 5000) {                       // cvt tree messages to bf16
        const int i = (bid * 256 + tid) * 4;
        if (i < M_N * HD) {
            const float4 v = *(const float4*)(tmsg + i);
            ushort4 o;
            o.x = f2b(v.x); o.y = f2b(v.y); o.z = f2b(v.z); o.w = f2b(v.w);
            *(ushort4*)(g_tmsgh + i) = o;
        }
    } else if (bid < 5032) {                // packW: split-bf16 MFMA fragments
        const int id = (bid - 5000) * 256 + tid;   // 0..8191
        const int l = id & 63;
        const int t = (id >> 6) & 15;
        const int c = id >> 10;
        const int n = t * 16 + (l & 15);
        const int kb = c * 32 + ((l >> 4) << 3);
        const size_t base = (size_t)id * 8;
        #pragma unroll
        for (int j = 0; j < 8; ++j) {
            const int k = kb + j;
            const float wh = Wh[(size_t)k * HD + n];
            const u16 hh = f2b(wh);
            g_pWh_hi[base + j] = hh;
            g_pWh_lo[base + j] = f2b(wh - b2f(hh));
            const float wo = Wo[(size_t)(35 + k) * HD + n];
            const u16 oh = f2b(wo);
            g_pWo_hi[base + j] = oh;
            g_pWo_lo[base + j] = f2b(wo - b2f(oh));
        }
    } else {                                // mstart via binary search (scope sorted)
        const int m = (bid - 5032) * 256 + tid;
        if (m <= N_MOLS) g_mstart[m] = lbound(scope, A_N, m);
    }
}

// ---------------- K1: binH = bf16(fbonds @ W_i); msg0 = bf16(relu(binput)) ----------------
// R12: W_i columns held in 160 VGPRs per lane (loaded once per persistent wave).
__global__ __launch_bounds__(256, 2)
void k_in(const float* __restrict__ fbonds, const float* __restrict__ Wi)
{
    const int lane = threadIdx.x & 63;
    const int wid  = (blockIdx.x * 256 + threadIdx.x) >> 6;
    const int nw   = (gridDim.x * 256) >> 6;

    float4 w[FB_DIM];                                  // 160 VGPR: W_i[:, lane*4..+4)
    #pragma unroll
    for (int k = 0; k < FB_DIM; ++k)
        w[k] = *(const float4*)&Wi[(size_t)k * HD + lane * 4];

    #pragma unroll 1
    for (int row = wid; row < B_N; row += nw) {
        const float* fr = fbonds + (size_t)row * FB_DIM;
        float ax = 0.f, ay = 0.f, az = 0.f, aw = 0.f;
        #pragma unroll
        for (int q = 0; q < FB_DIM / 4; ++q) {
            const float4 fv = *(const float4*)(fr + q * 4);
            ax += fv.x * w[q*4+0].x; ay += fv.x * w[q*4+0].y;
            az += fv.x * w[q*4+0].z; aw += fv.x * w[q*4+0].w;
            ax += fv.y * w[q*4+1].x; ay += fv.y * w[q*4+1].y;
            az += fv.y * w[q*4+1].z; aw += fv.y * w[q*4+1].w;
            ax += fv.z * w[q*4+2].x; ay += fv.z * w[q*4+2].y;
            az += fv.z * w[q*4+2].z; aw += fv.z * w[q*4+2].w;
            ax += fv.w * w[q*4+3].x; ay += fv.w * w[q*4+3].y;
            az += fv.w * w[q*4+3].z; aw += fv.w * w[q*4+3].w;
        }
        const size_t base = (size_t)row * HD + lane * 4;
        ushort4 bi;
        bi.x = f2b(ax); bi.y = f2b(ay); bi.z = f2b(az); bi.w = f2b(aw);
        *(ushort4*)(g_binH + base) = bi;
        ushort4 o;
        o.x = f2b(fmaxf(ax, 0.f)); o.y = f2b(fmaxf(ay, 0.f));
        o.z = f2b(fmaxf(az, 0.f)); o.w = f2b(fmaxf(aw, 0.f));
        *(ushort4*)(g_msg0 + base) = o;
    }
}

// ------- K2: MFMA GEMM — dst[row] = bf16(pool[row] @ W) with split-bf16 W -------
// R11: wave tile 64 rows x 128 cols; acc[4][8] static.  R13: manual prefetch of
// next c-iteration's 4 B-fragments into named registers.
__global__ __launch_bounds__(256, 2)
void k_gemmMF(int sel, int rowStart, int rowEnd)
{
    const u16* msrc = (sel == 1) ? g_msg1 : g_msg0;
    const u16* pHi  = (sel == 2) ? g_pWo_hi : g_pWh_hi;
    const u16* pLo  = (sel == 2) ? g_pWo_lo : g_pWh_lo;
    u16* dst        = (sel == 2) ? g_Q : g_P;

    const int tid  = threadIdx.x;
    const int lane = tid & 63;
    const int wv   = tid >> 6;            // 0..3
    const int l15  = lane & 15;
    const int quad = lane >> 4;
    const int tOff = (wv & 1) * 8;        // col-half: tiles [tOff, tOff+8)

    int rowIdeal[4];
    const u16* srow[4];
    #pragma unroll
    for (int rg = 0; rg < 4; ++rg) {
        const int ri = rowStart + blockIdx.x * 128 + (wv >> 1) * 64 + rg * 16 + l15;
        rowIdeal[rg] = ri;
        const int r = (ri < rowEnd) ? ri : (rowEnd - 1);
        srow[rg] = (r < M_N) ? (g_tmsgh + (size_t)r * HD)
                             : (msrc + (size_t)(r - M_N) * HD);
    }

    f32x4 acc[4][8];
    #pragma unroll
    for (int rg = 0; rg < 4; ++rg)
        #pragma unroll
        for (int t = 0; t < 8; ++t)
            acc[rg][t] = (f32x4){0.f, 0.f, 0.f, 0.f};

    bf16x8 b0 = *(const bf16x8*)(srow[0] + quad * 8);
    bf16x8 b1 = *(const bf16x8*)(srow[1] + quad * 8);
    bf16x8 b2 = *(const bf16x8*)(srow[2] + quad * 8);
    bf16x8 b3 = *(const bf16x8*)(srow[3] + quad * 8);

    #pragma unroll 1
    for (int c = 0; c < 8; ++c) {
        const int cn = (c + 1) & 7;        // wrap: iter 7 re-reads c=0 (harmless)
        const bf16x8 n0 = *(const bf16x8*)(srow[0] + cn * 32 + quad * 8);
        const bf16x8 n1 = *(const bf16x8*)(srow[1] + cn * 32 + quad * 8);
        const bf16x8 n2 = *(const bf16x8*)(srow[2] + cn * 32 + quad * 8);
        const bf16x8 n3 = *(const bf16x8*)(srow[3] + cn * 32 + quad * 8);
        const u16* ph = pHi + ((size_t)(c * 16 + tOff) * 64 + lane) * 8;
        const u16* pl = pLo + ((size_t)(c * 16 + tOff) * 64 + lane) * 8;
        #pragma unroll
        for (int t = 0; t < 8; ++t) {
            const bf16x8 ah = *(const bf16x8*)(ph + (size_t)t * 512);
            acc[0][t] = __builtin_amdgcn_mfma_f32_16x16x32_bf16(ah, b0, acc[0][t], 0, 0, 0);
            acc[1][t] = __builtin_amdgcn_mfma_f32_16x16x32_bf16(ah, b1, acc[1][t], 0, 0, 0);
            acc[2][t] = __builtin_amdgcn_mfma_f32_16x16x32_bf16(ah, b2, acc[2][t], 0, 0, 0);
            acc[3][t] = __builtin_amdgcn_mfma_f32_16x16x32_bf16(ah, b3, acc[3][t], 0, 0, 0);
            const bf16x8 al = *(const bf16x8*)(pl + (size_t)t * 512);
            acc[0][t] = __builtin_amdgcn_mfma_f32_16x16x32_bf16(al, b0, acc[0][t], 0, 0, 0);
            acc[1][t] = __builtin_amdgcn_mfma_f32_16x16x32_bf16(al, b1, acc[1][t], 0, 0, 0);
            acc[2][t] = __builtin_amdgcn_mfma_f32_16x16x32_bf16(al, b2, acc[2][t], 0, 0, 0);
            acc[3][t] = __builtin_amdgcn_mfma_f32_16x16x32_bf16(al, b3, acc[3][t], 0, 0, 0);
        }
        b0 = n0; b1 = n1; b2 = n2; b3 = n3;
    }

    #pragma unroll
    for (int rg = 0; rg < 4; ++rg) {
        if (rowIdeal[rg] < rowEnd) {
            u16* drow = dst + (size_t)rowIdeal[rg] * HD + tOff * 16 + quad * 4;
            #pragma unroll
            for (int t = 0; t < 8; ++t) {
                ushort4 o;
                o.x = f2b(acc[rg][t][0]); o.y = f2b(acc[rg][t][1]);
                o.z = f2b(acc[rg][t][2]); o.w = f2b(acc[rg][t][3]);
                *(ushort4*)(drow + t * 16) = o;
            }
        }
    }
}

// ------- K3: dst = bf16(relu(binH + sum_j P[bgraph[r][j]])) — pure gather -------
// R13: row-chunked (rowOff) for profile visibility.
__global__ __launch_bounds__(256)
void k_gather(const int* __restrict__ bgraph, int dstSel, int rowOff)
{
    u16* dst = dstSel ? g_msg1 : g_msg0;
    __shared__ int idx_s[8][MAX_NB];
    const int tid = threadIdx.x;
    const int rowBase = rowOff + blockIdx.x * 8;
    if (tid < 8 * MAX_NB) {
        const int r = tid / MAX_NB;
        const int j = tid - r * MAX_NB;
        idx_s[r][j] = bgraph[(size_t)(rowBase + r) * MAX_NB + j];
    }
    __syncthreads();
    const int rl = tid >> 5;           // [0,8)
    const int c  = (tid & 31) << 3;    // 8 bf16 = 16 B per thread
    const int row = rowBase + rl;

    const uint4 bv = *(const uint4*)(g_binH + (size_t)row * HD + c);
    float s[8] = {0.f,0.f,0.f,0.f,0.f,0.f,0.f,0.f};
    #pragma unroll
    for (int j = 0; j < MAX_NB; ++j) {
        const uint4 v = *(const uint4*)(g_P + (size_t)idx_s[rl][j] * HD + c);
        s[0] += blo(v.x); s[1] += bhi(v.x);
        s[2] += blo(v.y); s[3] += bhi(v.y);
        s[4] += blo(v.z); s[5] += bhi(v.z);
        s[6] += blo(v.w); s[7] += bhi(v.w);
    }
    uint4 w;
    w.x = ((unsigned)f2b(fmaxf(s[0] + blo(bv.x), 0.f)))
        | ((unsigned)f2b(fmaxf(s[1] + bhi(bv.x), 0.f)) << 16);
    w.y = ((unsigned)f2b(fmaxf(s[2] + blo(bv.y), 0.f)))
        | ((unsigned)f2b(fmaxf(s[3] + bhi(bv.y), 0.f)) << 16);
    w.z = ((unsigned)f2b(fmaxf(s[4] + blo(bv.z), 0.f)))
        | ((unsigned)f2b(fmaxf(s[5] + bhi(bv.z), 0.f)) << 16);
    w.w = ((unsigned)f2b(fmaxf(s[6] + blo(bv.w), 0.f)))
        | ((unsigned)f2b(fmaxf(s[7] + bhi(bv.w), 0.f)) << 16);
    *(uint4*)(dst + (size_t)row * HD + c) = w;
}

// ------- K4: Fh = bf16(fatoms @ Wo[0:35] + bias) -------
__global__ __launch_bounds__(256, 2)
void k_F(const float* __restrict__ fatoms, const float* __restrict__ Wo,
         const float* __restrict__ bias)
{
    const int lane = threadIdx.x & 63;
    const int wid  = (blockIdx.x * 256 + threadIdx.x) >> 6;
    const int nw   = (gridDim.x * 256) >> 6;

    float4 w[ATOM_FDIM];                               // 140 VGPR
    #pragma unroll
    for (int k = 0; k < ATOM_FDIM; ++k)
        w[k] = *(const float4*)&Wo[(size_t)k * HD + lane * 4];
    const float4 b4 = *(const float4*)&bias[lane * 4];

    #pragma unroll 1
    for (int row = wid; row < A_N; row += nw) {
        const float* fr = fatoms + (size_t)row * ATOM_FDIM;
        float ax = b4.x, ay = b4.y, az = b4.z, aw = b4.w;
        #pragma unroll
        for (int k = 0; k < ATOM_FDIM; ++k) {
            const float f = fr[k];
            ax += f * w[k].x; ay += f * w[k].y;
            az += f * w[k].z; aw += f * w[k].w;
        }
        ushort4 o;
        o.x = f2b(ax); o.y = f2b(ay); o.z = f2b(az); o.w = f2b(aw);
        *(ushort4*)(g_Fh + (size_t)row * HD + lane * 4) = o;
    }
}

// ------- K5: out[mol] = mean_a relu(Fh[a] + sum_j Q[agraph[a][j]]) -------
// R14: one block per (molecule, column-half); scope is sorted so molecules are
// contiguous atom ranges [mstart[m], mstart[m+1]).  16 groups x 16 threads
// stride the atoms; register partials -> LDS tree-reduce -> direct store of the
// mean.  Eliminates ALL global atomics (R13 counters: 111 MB HBM write-back
// from cross-XCD atomic line bouncing on a 2 MB output) and lifts occupancy
// (1563 -> 4000 blocks; was 49.7%).  k_div + out-zeroing folded in.
__global__ __launch_bounds__(256)
void k_gatherA(const int* __restrict__ agraph, float* __restrict__ out)
{
    const int mol = blockIdx.x >> 1;
    const int ch  = (blockIdx.x & 1) * 128;      // column half
    const int tid = threadIdx.x;
    const int grp = tid >> 4;                    // 16 groups
    const int lc  = (tid & 15) * 8;              // local col [0,128)
    const int c   = ch + lc;

    const int s0 = g_mstart[mol];
    const int s1 = g_mstart[mol + 1];

    float s[8] = {0.f,0.f,0.f,0.f,0.f,0.f,0.f,0.f};
    #pragma unroll 1
    for (int a = s0 + grp; a < s1; a += 16) {
        const int* ap = agraph + (size_t)a * MAX_NB;
        int idx[MAX_NB];
        #pragma unroll
        for (int j = 0; j < MAX_NB; ++j) idx[j] = ap[j];
        const uint4 fv = *(const uint4*)(g_Fh + (size_t)a * HD + c);
        float g0=0.f,g1=0.f,g2=0.f,g3=0.f,g4=0.f,g5=0.f,g6=0.f,g7=0.f;
        #pragma unroll
        for (int j = 0; j < MAX_NB; ++j) {
            const uint4 v = *(const uint4*)(g_Q + (size_t)idx[j] * HD + c);
            g0 += blo(v.x); g1 += bhi(v.x);
            g2 += blo(v.y); g3 += bhi(v.y);
            g4 += blo(v.z); g5 += bhi(v.z);
            g6 += blo(v.w); g7 += bhi(v.w);
        }
        s[0] += fmaxf(g0 + blo(fv.x), 0.f); s[1] += fmaxf(g1 + bhi(fv.x), 0.f);
        s[2] += fmaxf(g2 + blo(fv.y), 0.f); s[3] += fmaxf(g3 + bhi(fv.y), 0.f);
        s[4] += fmaxf(g4 + blo(fv.z), 0.f); s[5] += fmaxf(g5 + bhi(fv.z), 0.f);
        s[6] += fmaxf(g6 + blo(fv.w), 0.f); s[7] += fmaxf(g7 + bhi(fv.w), 0.f);
    }

    // reduce 16 group-partials: red[grp][lc..lc+8)
    __shared__ float red[16][128];               // 8 KB
    #pragma unroll
    for (int q = 0; q < 8; ++q) red[grp][lc + q] = s[q];
    __syncthreads();
    if (tid < 128) {
        float acc = 0.f;
        #pragma unroll
        for (int g = 0; g < 16; ++g) acc += red[g][tid];
        const float inv = 1.0f / fmaxf((float)(s1 - s0), 1.0f);
        out[(size_t)mol * HD + ch + tid] = acc * inv;
    }
}

// ---------------- launch ----------------
extern "C" void kernel_launch(void* const* d_in, const int* in_sizes, int n_in,
                              void* d_out, int out_size, void* d_ws, size_t ws_size,
                              hipStream_t stream)
{
    const float* fatoms = (const float*)d_in[0];
    const float* fbonds = (const float*)d_in[1];
    const int*   agraph = (const int*)d_in[2];
    const int*   bgraph = (const int*)d_in[3];
    const float* tmsg   = (const float*)d_in[4];
    const int*   scope  = (const int*)d_in[5];
    const float* W_i    = (const float*)d_in[6];
    const float* W_h    = (const float*)d_in[7];
    const float* W_o    = (const float*)d_in[8];
    const float* W_ob   = (const float*)d_in[9];
    float* out = (float*)d_out;

    (void)d_ws; (void)ws_size;

    k_setup<<<5040, 256, 0, stream>>>(tmsg, W_h, W_o, scope);
    k_in<<<512, 256, 0, stream>>>(fbonds, W_i);             // binH + msg0 (persistent)

    // iter 0: P = [tmsg; msg0] @ Wh; msg1 = relu(binH + gatherP)
    k_gemmMF<<<(POOL_N + 127) / 128, 256, 0, stream>>>(0, 0, POOL_N);
    for (int ch = 0; ch < 4; ++ch)
        k_gather<<<B_N / 32, 256, 0, stream>>>(bgraph, 1, ch * (B_N / 4));
    // iter 1: only msg rows of P change
    k_gemmMF<<<(B_N + 127) / 128, 256, 0, stream>>>(1, M_N, POOL_N);
    for (int ch = 0; ch < 4; ++ch)
        k_gather<<<B_N / 32, 256, 0, stream>>>(bgraph, 0, ch * (B_N / 4));

    // readout: Q = [tmsg; msg0] @ Wo[35:291]; Fh = fatoms@Wo[0:35]+b; gather+mean
    k_gemmMF<<<(POOL_N + 127) / 128, 256, 0, stream>>>(2, 0, POOL_N);
    k_F<<<512, 256, 0, stream>>>(fatoms, W_o, W_ob);
    k_gatherA<<<N_MOLS * 2, 256, 0, stream>>>(agraph, out);
}

// Round 5
// 1109.373 us; speedup vs baseline: 1.3408x; 1.0816x over previous
//
#include <hip/hip_runtime.h>
#include <cstdint>
#include <cstddef>

#define A_N 100000
#define B_N 200000
#define M_N 20000
#define POOL_N 220000   // M_N + B_N
#define HD 256
#define MAX_NB 10
#define N_MOLS 2000
#define ATOM_FDIM 35
#define FB_DIM 40

typedef unsigned short u16;
typedef __attribute__((ext_vector_type(8))) short bf16x8;
typedef __attribute__((ext_vector_type(4))) float f32x4;

// Static device buffers (BSS).
__device__ u16 g_msg0[(size_t)B_N * HD];      // bf16 messages (ping)
__device__ u16 g_msg1[(size_t)B_N * HD];      // bf16 messages (pong)
__device__ u16 g_tmsgh[(size_t)M_N * HD];     // bf16 tree messages
__device__ u16 g_P[(size_t)POOL_N * HD];      // P = pool @ W_h   (bf16)
__device__ u16 g_Q[(size_t)POOL_N * HD];      // Q = pool @ Wo[35:291] (bf16)
__device__ u16 g_binH[(size_t)B_N * HD];      // bf16 binput
__device__ u16 g_Fh[(size_t)A_N * HD];        // bf16 fatoms@Wo_top + bias
// packed split-bf16 weights in MFMA A-fragment order: [(c*16+t)*64+lane]*8+j
__device__ u16 g_pWh_hi[65536], g_pWh_lo[65536];
__device__ u16 g_pWo_hi[65536], g_pWo_lo[65536];
__device__ int g_mstart[N_MOLS + 1];          // molecule atom-range starts

__device__ __forceinline__ u16 f2b(float f)
{
    union { float f; unsigned u; } x; x.f = f;
    const unsigned r = x.u + 0x7FFFu + ((x.u >> 16) & 1u);
    return (u16)(r >> 16);
}
__device__ __forceinline__ float b2f(u16 h) { return __uint_as_float((unsigned)h << 16); }
__device__ __forceinline__ float blo(unsigned u) { return __uint_as_float(u << 16); }
__device__ __forceinline__ float bhi(unsigned u) { return __uint_as_float(u & 0xffff0000u); }

__device__ __forceinline__ int lbound(const int* __restrict__ s, int n, int v)
{
    int l = 0, r = n;
    while (l < r) { const int mid = (l + r) >> 1; if (s[mid] < v) l = mid + 1; else r = mid; }
    return l;
}

// async global->LDS, 16 B per lane (wave-uniform LDS base + lane*16; both our
// global src and LDS dst are linear in tid, so the copy is a straight memcpy).
__device__ __forceinline__ void gl_lds16(const u16* g, u16* l)
{
    __builtin_amdgcn_global_load_lds(
        (const __attribute__((address_space(1))) unsigned int*)g,
        (__attribute__((address_space(3))) unsigned int*)l,
        16, 0, 0);
}

// ---------------- K0: fused setup ----------------
// Segments by blockIdx: [0,5000) cvt tmsg->bf16; [5000,5032) packW;
// [5032,5040) mstart (binary search on sorted scope; 2001 entries).
__global__ __launch_bounds__(256)
void k_setup(const float* __restrict__ tmsg,
             const float* __restrict__ Wh, const float* __restrict__ Wo,
             const int* __restrict__ scope)
{
    const int bid = blockIdx.x;
    const int tid = threadIdx.x;
    if (bid < 5000) {                       // cvt tree messages to bf16
        const int i = (bid * 256 + tid) * 4;
        if (i < M_N * HD) {
            const float4 v = *(const float4*)(tmsg + i);
            ushort4 o;
            o.x = f2b(v.x); o.y = f2b(v.y); o.z = f2b(v.z); o.w = f2b(v.w);
            *(ushort4*)(g_tmsgh + i) = o;
        }
    } else if (bid < 5032) {                // packW: split-bf16 MFMA fragments
        const int id = (bid - 5000) * 256 + tid;   // 0..8191
        const int l = id & 63;
        const int t = (id >> 6) & 15;
        const int c = id >> 10;
        const int n = t * 16 + (l & 15);
        const int kb = c * 32 + ((l >> 4) << 3);
        const size_t base = (size_t)id * 8;
        #pragma unroll
        for (int j = 0; j < 8; ++j) {
            const int k = kb + j;
            const float wh = Wh[(size_t)k * HD + n];
            const u16 hh = f2b(wh);
            g_pWh_hi[base + j] = hh;
            g_pWh_lo[base + j] = f2b(wh - b2f(hh));
            const float wo = Wo[(size_t)(35 + k) * HD + n];
            const u16 oh = f2b(wo);
            g_pWo_hi[base + j] = oh;
            g_pWo_lo[base + j] = f2b(wo - b2f(oh));
        }
    } else {                                // mstart via binary search (scope sorted)
        const int m = (bid - 5032) * 256 + tid;
        if (m <= N_MOLS) g_mstart[m] = lbound(scope, A_N, m);
    }
}

// ---------------- K1: binH = bf16(fbonds @ W_i); msg0 = bf16(relu(binput)) ----------------
// R12: W_i columns held in 160 VGPRs per lane (loaded once per persistent wave).
__global__ __launch_bounds__(256, 2)
void k_in(const float* __restrict__ fbonds, const float* __restrict__ Wi)
{
    const int lane = threadIdx.x & 63;
    const int wid  = (blockIdx.x * 256 + threadIdx.x) >> 6;
    const int nw   = (gridDim.x * 256) >> 6;

    float4 w[FB_DIM];                                  // 160 VGPR: W_i[:, lane*4..+4)
    #pragma unroll
    for (int k = 0; k < FB_DIM; ++k)
        w[k] = *(const float4*)&Wi[(size_t)k * HD + lane * 4];

    #pragma unroll 1
    for (int row = wid; row < B_N; row += nw) {
        const float* fr = fbonds + (size_t)row * FB_DIM;
        float ax = 0.f, ay = 0.f, az = 0.f, aw = 0.f;
        #pragma unroll
        for (int q = 0; q < FB_DIM / 4; ++q) {
            const float4 fv = *(const float4*)(fr + q * 4);
            ax += fv.x * w[q*4+0].x; ay += fv.x * w[q*4+0].y;
            az += fv.x * w[q*4+0].z; aw += fv.x * w[q*4+0].w;
            ax += fv.y * w[q*4+1].x; ay += fv.y * w[q*4+1].y;
            az += fv.y * w[q*4+1].z; aw += fv.y * w[q*4+1].w;
            ax += fv.z * w[q*4+2].x; ay += fv.z * w[q*4+2].y;
            az += fv.z * w[q*4+2].z; aw += fv.z * w[q*4+2].w;
            ax += fv.w * w[q*4+3].x; ay += fv.w * w[q*4+3].y;
            az += fv.w * w[q*4+3].z; aw += fv.w * w[q*4+3].w;
        }
        const size_t base = (size_t)row * HD + lane * 4;
        ushort4 bi;
        bi.x = f2b(ax); bi.y = f2b(ay); bi.z = f2b(az); bi.w = f2b(aw);
        *(ushort4*)(g_binH + base) = bi;
        ushort4 o;
        o.x = f2b(fmaxf(ax, 0.f)); o.y = f2b(fmaxf(ay, 0.f));
        o.z = f2b(fmaxf(az, 0.f)); o.w = f2b(fmaxf(aw, 0.f));
        *(ushort4*)(g_msg0 + base) = o;
    }
}

// ------- K2: MFMA GEMM — dst[row] = bf16(pool[row] @ W) with split-bf16 W -------
// R15: R14 counters showed MfmaUtil 17%, VALUBusy 10%, HBM 18% — latency-bound.
// Cause: 16 independent A-frag loads/c-step from L2 (~250cyc) need 64 VGPRs in
// flight; at ~220/256 regs the compiler serialized them (16 L2 round trips per
// c-step vs 310 cyc of MFMA). Fix: stage each c-step's 32 KB weight slab
// (hi+lo, both col-halves) into LDS with async global_load_lds (zero VGPR),
// double-buffered (64 KB), ONE __syncthreads per c-step. The barrier's
// vmcnt(0) drain is the buffer-ready guarantee. Race-check: buf written at
// iter c was last read at compute(c-1), which precedes barrier(c) for all
// waves. MFMAs read A-frags via ds_read_b128 (~120 cyc, compiler lgkmcnt).
__global__ __launch_bounds__(256, 2)
void k_gemmMF(int sel, int rowStart, int rowEnd)
{
    const u16* msrc = (sel == 1) ? g_msg1 : g_msg0;
    const u16* pHi  = (sel == 2) ? g_pWo_hi : g_pWh_hi;
    const u16* pLo  = (sel == 2) ? g_pWo_lo : g_pWh_lo;
    u16* dst        = (sel == 2) ? g_Q : g_P;

    __shared__ u16 lds[2][16384];         // 64 KB: [buf][hi 8192 | lo 8192]

    const int tid  = threadIdx.x;
    const int lane = tid & 63;
    const int wv   = tid >> 6;            // 0..3
    const int l15  = lane & 15;
    const int quad = lane >> 4;
    const int tOff = (wv & 1) * 8;        // col-half: tiles [tOff, tOff+8)

    int rowIdeal[4];
    const u16* srow[4];
    #pragma unroll
    for (int rg = 0; rg < 4; ++rg) {
        const int ri = rowStart + blockIdx.x * 128 + (wv >> 1) * 64 + rg * 16 + l15;
        rowIdeal[rg] = ri;
        const int r = (ri < rowEnd) ? ri : (rowEnd - 1);
        srow[rg] = (r < M_N) ? (g_tmsgh + (size_t)r * HD)
                             : (msrc + (size_t)(r - M_N) * HD);
    }

    // stage c-step cc's 16 KB hi + 16 KB lo into lds[bf] (linear copy)
    #define STAGE(bf, cc) do {                                            \
        const u16* sh_ = pHi + (cc) * 8192 + tid * 8;                     \
        const u16* sl_ = pLo + (cc) * 8192 + tid * 8;                     \
        u16* dh_ = &lds[bf][tid * 8];                                     \
        u16* dl_ = &lds[bf][8192 + tid * 8];                              \
        gl_lds16(sh_,        dh_);                                        \
        gl_lds16(sh_ + 2048, dh_ + 2048);                                 \
        gl_lds16(sh_ + 4096, dh_ + 4096);                                 \
        gl_lds16(sh_ + 6144, dh_ + 6144);                                 \
        gl_lds16(sl_,        dl_);                                        \
        gl_lds16(sl_ + 2048, dl_ + 2048);                                 \
        gl_lds16(sl_ + 4096, dl_ + 4096);                                 \
        gl_lds16(sl_ + 6144, dl_ + 6144);                                 \
    } while (0)

    f32x4 acc[4][8];
    #pragma unroll
    for (int rg = 0; rg < 4; ++rg)
        #pragma unroll
        for (int t = 0; t < 8; ++t)
            acc[rg][t] = (f32x4){0.f, 0.f, 0.f, 0.f};

    // prologue: stage c=0; preload B-row fragments for c=0
    STAGE(0, 0);
    bf16x8 b0 = *(const bf16x8*)(srow[0] + quad * 8);
    bf16x8 b1 = *(const bf16x8*)(srow[1] + quad * 8);
    bf16x8 b2 = *(const bf16x8*)(srow[2] + quad * 8);
    bf16x8 b3 = *(const bf16x8*)(srow[3] + quad * 8);

    #pragma unroll 1
    for (int c = 0; c < 8; ++c) {
        __syncthreads();                   // buf[c&1] staged (vmcnt drained) + all
                                           // waves done reading buf[(c+1)&1]
        if (c < 7) STAGE((c + 1) & 1, c + 1);   // overlaps with compute below

        const int cn = (c + 1) & 7;        // B-row prefetch (wrap re-reads c=0)
        const bf16x8 n0 = *(const bf16x8*)(srow[0] + cn * 32 + quad * 8);
        const bf16x8 n1 = *(const bf16x8*)(srow[1] + cn * 32 + quad * 8);
        const bf16x8 n2 = *(const bf16x8*)(srow[2] + cn * 32 + quad * 8);
        const bf16x8 n3 = *(const bf16x8*)(srow[3] + cn * 32 + quad * 8);

        const u16* Lh = &lds[c & 1][(size_t)tOff * 512 + lane * 8];
        const u16* Ll = Lh + 8192;
        #pragma unroll
        for (int t = 0; t < 8; ++t) {
            const bf16x8 ah = *(const bf16x8*)(Lh + t * 512);
            acc[0][t] = __builtin_amdgcn_mfma_f32_16x16x32_bf16(ah, b0, acc[0][t], 0, 0, 0);
            acc[1][t] = __builtin_amdgcn_mfma_f32_16x16x32_bf16(ah, b1, acc[1][t], 0, 0, 0);
            acc[2][t] = __builtin_amdgcn_mfma_f32_16x16x32_bf16(ah, b2, acc[2][t], 0, 0, 0);
            acc[3][t] = __builtin_amdgcn_mfma_f32_16x16x32_bf16(ah, b3, acc[3][t], 0, 0, 0);
            const bf16x8 al = *(const bf16x8*)(Ll + t * 512);
            acc[0][t] = __builtin_amdgcn_mfma_f32_16x16x32_bf16(al, b0, acc[0][t], 0, 0, 0);
            acc[1][t] = __builtin_amdgcn_mfma_f32_16x16x32_bf16(al, b1, acc[1][t], 0, 0, 0);
            acc[2][t] = __builtin_amdgcn_mfma_f32_16x16x32_bf16(al, b2, acc[2][t], 0, 0, 0);
            acc[3][t] = __builtin_amdgcn_mfma_f32_16x16x32_bf16(al, b3, acc[3][t], 0, 0, 0);
        }
        b0 = n0; b1 = n1; b2 = n2; b3 = n3;
    }
    #undef STAGE

    #pragma unroll
    for (int rg = 0; rg < 4; ++rg) {
        if (rowIdeal[rg] < rowEnd) {
            u16* drow = dst + (size_t)rowIdeal[rg] * HD + tOff * 16 + quad * 4;
            #pragma unroll
            for (int t = 0; t < 8; ++t) {
                ushort4 o;
                o.x = f2b(acc[rg][t][0]); o.y = f2b(acc[rg][t][1]);
                o.z = f2b(acc[rg][t][2]); o.w = f2b(acc[rg][t][3]);
                *(ushort4*)(drow + t * 16) = o;
            }
        }
    }
}

// ------- K3: dst = bf16(relu(binH + sum_j P[bgraph[r][j]])) — pure gather -------
__global__ __launch_bounds__(256)
void k_gather(const int* __restrict__ bgraph, int dstSel, int rowOff)
{
    u16* dst = dstSel ? g_msg1 : g_msg0;
    __shared__ int idx_s[8][MAX_NB];
    const int tid = threadIdx.x;
    const int rowBase = rowOff + blockIdx.x * 8;
    if (tid < 8 * MAX_NB) {
        const int r = tid / MAX_NB;
        const int j = tid - r * MAX_NB;
        idx_s[r][j] = bgraph[(size_t)(rowBase + r) * MAX_NB + j];
    }
    __syncthreads();
    const int rl = tid >> 5;           // [0,8)
    const int c  = (tid & 31) << 3;    // 8 bf16 = 16 B per thread
    const int row = rowBase + rl;

    const uint4 bv = *(const uint4*)(g_binH + (size_t)row * HD + c);
    float s[8] = {0.f,0.f,0.f,0.f,0.f,0.f,0.f,0.f};
    #pragma unroll
    for (int j = 0; j < MAX_NB; ++j) {
        const uint4 v = *(const uint4*)(g_P + (size_t)idx_s[rl][j] * HD + c);
        s[0] += blo(v.x); s[1] += bhi(v.x);
        s[2] += blo(v.y); s[3] += bhi(v.y);
        s[4] += blo(v.z); s[5] += bhi(v.z);
        s[6] += blo(v.w); s[7] += bhi(v.w);
    }
    uint4 w;
    w.x = ((unsigned)f2b(fmaxf(s[0] + blo(bv.x), 0.f)))
        | ((unsigned)f2b(fmaxf(s[1] + bhi(bv.x), 0.f)) << 16);
    w.y = ((unsigned)f2b(fmaxf(s[2] + blo(bv.y), 0.f)))
        | ((unsigned)f2b(fmaxf(s[3] + bhi(bv.y), 0.f)) << 16);
    w.z = ((unsigned)f2b(fmaxf(s[4] + blo(bv.z), 0.f)))
        | ((unsigned)f2b(fmaxf(s[5] + bhi(bv.z), 0.f)) << 16);
    w.w = ((unsigned)f2b(fmaxf(s[6] + blo(bv.w), 0.f)))
        | ((unsigned)f2b(fmaxf(s[7] + bhi(bv.w), 0.f)) << 16);
    *(uint4*)(dst + (size_t)row * HD + c) = w;
}

// ------- K4: Fh = bf16(fatoms @ Wo[0:35] + bias) -------
__global__ __launch_bounds__(256, 2)
void k_F(const float* __restrict__ fatoms, const float* __restrict__ Wo,
         const float* __restrict__ bias)
{
    const int lane = threadIdx.x & 63;
    const int wid  = (blockIdx.x * 256 + threadIdx.x) >> 6;
    const int nw   = (gridDim.x * 256) >> 6;

    float4 w[ATOM_FDIM];                               // 140 VGPR
    #pragma unroll
    for (int k = 0; k < ATOM_FDIM; ++k)
        w[k] = *(const float4*)&Wo[(size_t)k * HD + lane * 4];
    const float4 b4 = *(const float4*)&bias[lane * 4];

    #pragma unroll 1
    for (int row = wid; row < A_N; row += nw) {
        const float* fr = fatoms + (size_t)row * ATOM_FDIM;
        float ax = b4.x, ay = b4.y, az = b4.z, aw = b4.w;
        #pragma unroll
        for (int k = 0; k < ATOM_FDIM; ++k) {
            const float f = fr[k];
            ax += f * w[k].x; ay += f * w[k].y;
            az += f * w[k].z; aw += f * w[k].w;
        }
        ushort4 o;
        o.x = f2b(ax); o.y = f2b(ay); o.z = f2b(az); o.w = f2b(aw);
        *(ushort4*)(g_Fh + (size_t)row * HD + lane * 4) = o;
    }
}

// ------- K5: out[mol] = mean_a relu(Fh[a] + sum_j Q[agraph[a][j]]) -------
// R14: one block per (molecule, column-half); no atomics; direct mean store.
__global__ __launch_bounds__(256)
void k_gatherA(const int* __restrict__ agraph, float* __restrict__ out)
{
    const int mol = blockIdx.x >> 1;
    const int ch  = (blockIdx.x & 1) * 128;      // column half
    const int tid = threadIdx.x;
    const int grp = tid >> 4;                    // 16 groups
    const int lc  = (tid & 15) * 8;              // local col [0,128)
    const int c   = ch + lc;

    const int s0 = g_mstart[mol];
    const int s1 = g_mstart[mol + 1];

    float s[8] = {0.f,0.f,0.f,0.f,0.f,0.f,0.f,0.f};
    #pragma unroll 1
    for (int a = s0 + grp; a < s1; a += 16) {
        const int* ap = agraph + (size_t)a * MAX_NB;
        int idx[MAX_NB];
        #pragma unroll
        for (int j = 0; j < MAX_NB; ++j) idx[j] = ap[j];
        const uint4 fv = *(const uint4*)(g_Fh + (size_t)a * HD + c);
        float g0=0.f,g1=0.f,g2=0.f,g3=0.f,g4=0.f,g5=0.f,g6=0.f,g7=0.f;
        #pragma unroll
        for (int j = 0; j < MAX_NB; ++j) {
            const uint4 v = *(const uint4*)(g_Q + (size_t)idx[j] * HD + c);
            g0 += blo(v.x); g1 += bhi(v.x);
            g2 += blo(v.y); g3 += bhi(v.y);
            g4 += blo(v.z); g5 += bhi(v.z);
            g6 += blo(v.w); g7 += bhi(v.w);
        }
        s[0] += fmaxf(g0 + blo(fv.x), 0.f); s[1] += fmaxf(g1 + bhi(fv.x), 0.f);
        s[2] += fmaxf(g2 + blo(fv.y), 0.f); s[3] += fmaxf(g3 + bhi(fv.y), 0.f);
        s[4] += fmaxf(g4 + blo(fv.z), 0.f); s[5] += fmaxf(g5 + bhi(fv.z), 0.f);
        s[6] += fmaxf(g6 + blo(fv.w), 0.f); s[7] += fmaxf(g7 + bhi(fv.w), 0.f);
    }

    // reduce 16 group-partials: red[grp][lc..lc+8)
    __shared__ float red[16][128];               // 8 KB
    #pragma unroll
    for (int q = 0; q < 8; ++q) red[grp][lc + q] = s[q];
    __syncthreads();
    if (tid < 128) {
        float acc = 0.f;
        #pragma unroll
        for (int g = 0; g < 16; ++g) acc += red[g][tid];
        const float inv = 1.0f / fmaxf((float)(s1 - s0), 1.0f);
        out[(size_t)mol * HD + ch + tid] = acc * inv;
    }
}

// ---------------- launch ----------------
extern "C" void kernel_launch(void* const* d_in, const int* in_sizes, int n_in,
                              void* d_out, int out_size, void* d_ws, size_t ws_size,
                              hipStream_t stream)
{
    const float* fatoms = (const float*)d_in[0];
    const float* fbonds = (const float*)d_in[1];
    const int*   agraph = (const int*)d_in[2];
    const int*   bgraph = (const int*)d_in[3];
    const float* tmsg   = (const float*)d_in[4];
    const int*   scope  = (const int*)d_in[5];
    const float* W_i    = (const float*)d_in[6];
    const float* W_h    = (const float*)d_in[7];
    const float* W_o    = (const float*)d_in[8];
    const float* W_ob   = (const float*)d_in[9];
    float* out = (float*)d_out;

    (void)d_ws; (void)ws_size;

    k_setup<<<5040, 256, 0, stream>>>(tmsg, W_h, W_o, scope);
    k_in<<<512, 256, 0, stream>>>(fbonds, W_i);             // binH + msg0 (persistent)

    // iter 0: P = [tmsg; msg0] @ Wh; msg1 = relu(binH + gatherP)
    k_gemmMF<<<(POOL_N + 127) / 128, 256, 0, stream>>>(0, 0, POOL_N);
    for (int ch = 0; ch < 4; ++ch)
        k_gather<<<B_N / 32, 256, 0, stream>>>(bgraph, 1, ch * (B_N / 4));
    // iter 1: only msg rows of P change
    k_gemmMF<<<(B_N + 127) / 128, 256, 0, stream>>>(1, M_N, POOL_N);
    for (int ch = 0; ch < 4; ++ch)
        k_gather<<<B_N / 32, 256, 0, stream>>>(bgraph, 0, ch * (B_N / 4));

    // readout: Q = [tmsg; msg0] @ Wo[35:291]; Fh = fatoms@Wo[0:35]+b; gather+mean
    k_gemmMF<<<(POOL_N + 127) / 128, 256, 0, stream>>>(2, 0, POOL_N);
    k_F<<<512, 256, 0, stream>>>(fatoms, W_o, W_ob);
    k_gatherA<<<N_MOLS * 2, 256, 0, stream>>>(agraph, out);
}